// Round 1
// baseline (1362.220 us; speedup 1.0000x reference)
//
#include <hip/hip_runtime.h>
#include <hip/hip_bf16.h>

// Fused GQA attention layer, fp32 baseline.
// B=1, S=2048, HID=2048, NH=32, NKV=8, HD=64, N_REP=4, SCALE=0.125.
// Pipeline: QKV proj (GEMM) -> RoPE -> flash causal attention -> out proj.

#define S_LEN 2048
#define HIDDEN 2048
#define NH 32
#define NKV 8
#define HD 64
#define SCALE 0.125f

// ---------------------------------------------------------------------------
// Generic C[m][n] = sum_k A[m][k] * B[n0+n][k]  (both row-major, ldk = 2048).
// Tile: BM=128 (blockIdx.x), BN=64 (blockIdx.y selects 64-row slice of B).
// C address = C + blockIdx.y*c_head_stride + m*c_row_stride + n.
//   Q/K/V proj: c_head_stride = S*HD (head-major out), c_row_stride = HD.
//   out proj:   c_head_stride = 64,                    c_row_stride = HIDDEN.
// ---------------------------------------------------------------------------
__global__ __launch_bounds__(256) void gemm_bt(
    const float* __restrict__ A, const float* __restrict__ Bw,
    float* __restrict__ C, long c_head_stride, int c_row_stride)
{
    __shared__ float As[32][132];  // [k][m], padded (132*4B = 528B, 16B-aligned rows)
    __shared__ float Bs[32][68];   // [k][n], padded (272B rows)

    const int tid = threadIdx.x;
    const int m0 = blockIdx.x * 128;
    const float* Bh = Bw + (long)blockIdx.y * 64 * HIDDEN;
    float* Cb = C + (long)blockIdx.y * c_head_stride + (long)m0 * c_row_stride;
    const int tx = tid & 15, ty = tid >> 4;

    float acc[8][4];
#pragma unroll
    for (int i = 0; i < 8; i++)
#pragma unroll
        for (int j = 0; j < 4; j++) acc[i][j] = 0.f;

    for (int k0 = 0; k0 < HIDDEN; k0 += 32) {
        // A tile 128x32 -> LDS transposed
#pragma unroll
        for (int p = 0; p < 4; p++) {
            int pos = tid + p * 256;
            int row = pos >> 3, c4 = pos & 7;
            float4 v = *(const float4*)(A + (long)(m0 + row) * HIDDEN + k0 + c4 * 4);
            As[c4 * 4 + 0][row] = v.x; As[c4 * 4 + 1][row] = v.y;
            As[c4 * 4 + 2][row] = v.z; As[c4 * 4 + 3][row] = v.w;
        }
        // B tile 64x32 -> LDS transposed
#pragma unroll
        for (int p = 0; p < 2; p++) {
            int pos = tid + p * 256;
            int row = pos >> 3, c4 = pos & 7;
            float4 v = *(const float4*)(Bh + (long)row * HIDDEN + k0 + c4 * 4);
            Bs[c4 * 4 + 0][row] = v.x; Bs[c4 * 4 + 1][row] = v.y;
            Bs[c4 * 4 + 2][row] = v.z; Bs[c4 * 4 + 3][row] = v.w;
        }
        __syncthreads();
#pragma unroll
        for (int kk = 0; kk < 32; kk++) {
            float a[8], b[4];
            *(float4*)&a[0] = *(const float4*)&As[kk][ty * 8];
            *(float4*)&a[4] = *(const float4*)&As[kk][ty * 8 + 4];
            *(float4*)&b[0] = *(const float4*)&Bs[kk][tx * 4];
#pragma unroll
            for (int i = 0; i < 8; i++)
#pragma unroll
                for (int j = 0; j < 4; j++)
                    acc[i][j] = fmaf(a[i], b[j], acc[i][j]);
        }
        __syncthreads();
    }
#pragma unroll
    for (int i = 0; i < 8; i++) {
        int m = ty * 8 + i;
        float4 o;
        o.x = acc[i][0]; o.y = acc[i][1]; o.z = acc[i][2]; o.w = acc[i][3];
        *(float4*)(Cb + (long)m * c_row_stride + tx * 4) = o;
    }
}

// ---------------------------------------------------------------------------
// In-place RoPE on Q ([NH][S][HD]) and K ([NKV][S][HD]).
// thread -> (slot, s, d) with d in [0,32); pairs (d, d+32) are disjoint.
// cos/sin tables: [S][HD], first and second halves identical by construction.
// ---------------------------------------------------------------------------
__global__ __launch_bounds__(256) void rope_kernel(
    float* __restrict__ q, float* __restrict__ k,
    const float* __restrict__ cosT, const float* __restrict__ sinT)
{
    int idx = blockIdx.x * 256 + threadIdx.x;  // (NH+NKV)*S*32 exact
    int d = idx & 31;
    int s = (idx >> 5) & (S_LEN - 1);
    int slot = idx >> 16;
    float* base = (slot < NH) ? (q + ((long)slot * S_LEN + s) * HD)
                              : (k + ((long)(slot - NH) * S_LEN + s) * HD);
    float c = cosT[s * HD + d];
    float sn = sinT[s * HD + d];
    float x1 = base[d], x2 = base[d + 32];
    base[d]      = x1 * c - x2 * sn;
    base[d + 32] = x2 * c + x1 * sn;
}

// ---------------------------------------------------------------------------
// Flash causal attention. Grid: (S/64 q-tiles, NH heads). Block 256 (4 waves).
// Q [NH][S][HD], K/V [NKV][S][HD]. Output Ow [S][NH*HD].
// Per kv-tile: K->LDS(transposed), scores (4x4 microtile), online softmax
// (4 lanes per row, shfl_xor reduce), V (reuses K LDS buffer), PV accumulate.
// ---------------------------------------------------------------------------
__global__ __launch_bounds__(256) void attn_kernel(
    const float* __restrict__ Qw, const float* __restrict__ Kw,
    const float* __restrict__ Vw, float* __restrict__ Ow)
{
    __shared__ float Qs[64][68];    // [d][m]
    __shared__ float KVs[64][68];   // K phase: [d][n]; V phase: [n][d]
    __shared__ float Ss[64][68];    // scores/probs [m][n]
    __shared__ float m_run[64], l_run[64], corr_s[64];

    const int tid = threadIdx.x;
    const int h = blockIdx.y;
    const int hk = h >> 2;  // N_REP = 4
    const int qt = blockIdx.x;
    const int q0 = qt * 64;
    const float* Qb = Qw + ((long)h * S_LEN + q0) * HD;
    const float* Kb = Kw + (long)hk * S_LEN * HD;
    const float* Vb = Vw + (long)hk * S_LEN * HD;
    const int tx = tid & 15, ty = tid >> 4;

    // Q tile -> LDS transposed [d][m]
#pragma unroll
    for (int p = 0; p < 4; p++) {
        int pos = tid + p * 256;
        int row = pos >> 4, c4 = pos & 15;
        float4 v = *(const float4*)(Qb + row * HD + c4 * 4);
        Qs[c4 * 4 + 0][row] = v.x; Qs[c4 * 4 + 1][row] = v.y;
        Qs[c4 * 4 + 2][row] = v.z; Qs[c4 * 4 + 3][row] = v.w;
    }
    if (tid < 64) { m_run[tid] = -1e30f; l_run[tid] = 0.f; }

    float accO[4][4];
#pragma unroll
    for (int i = 0; i < 4; i++)
#pragma unroll
        for (int j = 0; j < 4; j++) accO[i][j] = 0.f;

    const int lane = tid & 63, w = tid >> 6;
    const int r = lane >> 2, jj = lane & 3;
    const int srow = w * 16 + r;  // softmax row owned by this 4-lane group

    for (int t = 0; t <= qt; t++) {
        const int k0 = t * 64;
        __syncthreads();  // prev PV done with KVs/Ss (and Q store on t=0)
        // K tile -> LDS transposed [d][n]
#pragma unroll
        for (int p = 0; p < 4; p++) {
            int pos = tid + p * 256;
            int row = pos >> 4, c4 = pos & 15;
            float4 v = *(const float4*)(Kb + (long)(k0 + row) * HD + c4 * 4);
            KVs[c4 * 4 + 0][row] = v.x; KVs[c4 * 4 + 1][row] = v.y;
            KVs[c4 * 4 + 2][row] = v.z; KVs[c4 * 4 + 3][row] = v.w;
        }
        __syncthreads();
        // scores: 4x4 microtile over d
        float sc[4][4];
#pragma unroll
        for (int i = 0; i < 4; i++)
#pragma unroll
            for (int j = 0; j < 4; j++) sc[i][j] = 0.f;
#pragma unroll 8
        for (int d = 0; d < 64; d++) {
            float a[4], b[4];
            *(float4*)a = *(const float4*)&Qs[d][ty * 4];
            *(float4*)b = *(const float4*)&KVs[d][tx * 4];
#pragma unroll
            for (int i = 0; i < 4; i++)
#pragma unroll
                for (int j = 0; j < 4; j++)
                    sc[i][j] = fmaf(a[i], b[j], sc[i][j]);
        }
        const bool diag = (t == qt);
#pragma unroll
        for (int i = 0; i < 4; i++) {
            float4 o;
            float* po = &o.x;
#pragma unroll
            for (int j = 0; j < 4; j++) {
                float s = sc[i][j] * SCALE;
                if (diag && (tx * 4 + j) > (ty * 4 + i)) s = -1e30f;
                po[j] = s;
            }
            *(float4*)&Ss[ty * 4 + i][tx * 4] = o;
        }
        __syncthreads();  // Ss complete; KVs free

        // V tile -> regs (latency hides under softmax)
        float4 vr[4];
#pragma unroll
        for (int p = 0; p < 4; p++) {
            int pos = tid + p * 256;
            int row = pos >> 4, c4 = pos & 15;
            vr[p] = *(const float4*)(Vb + (long)(k0 + row) * HD + c4 * 4);
        }
        // online softmax: 4 lanes x 16 cols per row
        float mx = -1e30f;
#pragma unroll
        for (int c = 0; c < 16; c++) mx = fmaxf(mx, Ss[srow][jj * 16 + c]);
        mx = fmaxf(mx, __shfl_xor(mx, 1));
        mx = fmaxf(mx, __shfl_xor(mx, 2));
        float mold = m_run[srow];
        float mnew = fmaxf(mold, mx);
        float corr = __expf(mold - mnew);
        float sum = 0.f;
#pragma unroll
        for (int c = 0; c < 16; c++) {
            float pv = __expf(Ss[srow][jj * 16 + c] - mnew);
            Ss[srow][jj * 16 + c] = pv;
            sum += pv;
        }
        sum += __shfl_xor(sum, 1);
        sum += __shfl_xor(sum, 2);
        if (jj == 0) {
            m_run[srow] = mnew;
            l_run[srow] = l_run[srow] * corr + sum;
            corr_s[srow] = corr;
        }
        // V regs -> LDS [n][d] (KVs reuse; scores already synced)
#pragma unroll
        for (int p = 0; p < 4; p++) {
            int pos = tid + p * 256;
            int row = pos >> 4, c4 = pos & 15;
            *(float4*)&KVs[row][c4 * 4] = vr[p];
        }
        __syncthreads();  // P + V + corr ready
        // rescale accumulator, then PV
#pragma unroll
        for (int i = 0; i < 4; i++) {
            float cr = corr_s[ty * 4 + i];
#pragma unroll
            for (int j = 0; j < 4; j++) accO[i][j] *= cr;
        }
#pragma unroll 8
        for (int n = 0; n < 64; n++) {
            float b[4];
            *(float4*)b = *(const float4*)&KVs[n][tx * 4];
#pragma unroll
            for (int i = 0; i < 4; i++) {
                float pp = Ss[ty * 4 + i][n];
#pragma unroll
                for (int j = 0; j < 4; j++)
                    accO[i][j] = fmaf(pp, b[j], accO[i][j]);
            }
        }
    }
    // epilogue: divide by l, write O[s][h*64+d]
#pragma unroll
    for (int i = 0; i < 4; i++) {
        float inv = 1.0f / l_run[ty * 4 + i];
        float4 o;
        o.x = accO[i][0] * inv; o.y = accO[i][1] * inv;
        o.z = accO[i][2] * inv; o.w = accO[i][3] * inv;
        *(float4*)(Ow + (long)(q0 + ty * 4 + i) * (NH * HD) + h * HD + tx * 4) = o;
    }
}

// ---------------------------------------------------------------------------
extern "C" void kernel_launch(void* const* d_in, const int* in_sizes, int n_in,
                              void* d_out, int out_size, void* d_ws, size_t ws_size,
                              hipStream_t stream) {
    const float* hidden = (const float*)d_in[0];
    const float* cosT   = (const float*)d_in[1];
    const float* sinT   = (const float*)d_in[2];
    // d_in[3] = attention_mask: exactly causal -> implemented analytically
    const float* wq = (const float*)d_in[4];
    const float* wk = (const float*)d_in[5];
    const float* wv = (const float*)d_in[6];
    const float* wo = (const float*)d_in[7];
    float* out = (float*)d_out;

    float* ws = (float*)d_ws;
    float* q = ws;                       // [NH][S][HD]   16 MB
    float* k = q + (long)NH * S_LEN * HD;    // [NKV][S][HD]   4 MB
    float* v = k + (long)NKV * S_LEN * HD;   // [NKV][S][HD]   4 MB
    float* o = v + (long)NKV * S_LEN * HD;   // [S][NH*HD]    16 MB

    dim3 blk(256);
    // projections: C = hidden @ W^T
    gemm_bt<<<dim3(16, 32), blk, 0, stream>>>(hidden, wq, q, (long)S_LEN * HD, HD);
    gemm_bt<<<dim3(16, 8),  blk, 0, stream>>>(hidden, wk, k, (long)S_LEN * HD, HD);
    gemm_bt<<<dim3(16, 8),  blk, 0, stream>>>(hidden, wv, v, (long)S_LEN * HD, HD);
    // RoPE in place on q, k
    rope_kernel<<<(NH + NKV) * S_LEN * 32 / 256, blk, 0, stream>>>(q, k, cosT, sinT);
    // flash causal attention
    attn_kernel<<<dim3(S_LEN / 64, NH), blk, 0, stream>>>(q, k, v, o);
    // output projection: out = o @ wo^T
    gemm_bt<<<dim3(16, 32), blk, 0, stream>>>(o, wo, out, 64, HIDDEN);
}

// Round 2
// 770.899 us; speedup vs baseline: 1.7671x; 1.7671x over previous
//
#include <hip/hip_runtime.h>
#include <hip/hip_bf16.h>
#include <stdint.h>

// Fused GQA attention layer.
// Round 2: QKV + out projections via split-bf16 MFMA (hi/lo planes, 3-term
// product => fp32-like accuracy at ~794 TF effective ceiling).
// Attention kernel unchanged (fp32 flash) this round.

#define S_LEN 2048
#define HIDDEN 2048
#define NH 32
#define NKV 8
#define HD 64
#define SCALE 0.125f

typedef __bf16 bf16x8 __attribute__((ext_vector_type(8)));
typedef float f32x4 __attribute__((ext_vector_type(4)));

// global -> LDS direct (16B per lane). CK-style addrspace casts.
__device__ inline void gload16(const void* g, void* l) {
    using GP = const __attribute__((address_space(1))) uint32_t*;
    using LP = __attribute__((address_space(3))) uint32_t*;
    __builtin_amdgcn_global_load_lds((GP)g, (LP)(uint32_t)(uintptr_t)l, 16, 0, 0);
}

// ---------------------------------------------------------------------------
// fp32 -> (bf16 hi, bf16 lo) split, vectorized x4. Exact two-term split:
// hi = RNE-bf16(x); lo = RNE-bf16(x - hi).  a*b ~= ah*bh + ah*bl + al*bh.
// ---------------------------------------------------------------------------
__global__ __launch_bounds__(256) void split_bf16(
    const float* __restrict__ src, ushort* __restrict__ hi,
    ushort* __restrict__ lo, int n4)
{
    int i = blockIdx.x * 256 + threadIdx.x;
    if (i >= n4) return;
    float4 v = ((const float4*)src)[i];
    ushort h[4], l[4];
    float x[4] = {v.x, v.y, v.z, v.w};
#pragma unroll
    for (int j = 0; j < 4; j++) {
        uint32_t u = __float_as_uint(x[j]);
        uint32_t hr = (u + 0x7FFFu + ((u >> 16) & 1u)) >> 16;
        float hf = __uint_as_float(hr << 16);
        float r = x[j] - hf;
        uint32_t ul = __float_as_uint(r);
        uint32_t lr = (ul + 0x7FFFu + ((ul >> 16) & 1u)) >> 16;
        h[j] = (ushort)hr;
        l[j] = (ushort)lr;
    }
    ushort4 ho = {h[0], h[1], h[2], h[3]};
    ushort4 lv = {l[0], l[1], l[2], l[3]};
    ((ushort4*)hi)[i] = ho;
    ((ushort4*)lo)[i] = lv;
}

// ---------------------------------------------------------------------------
// Split-bf16 MFMA GEMM: C[m][n] = sum_k A[m][k]*Bw[n][k], K = 2048.
// Tile BM=64 x BN=128, BK=32, 256 threads (4 waves; wave w owns 64x32 cols).
// Planes: Ah/Al [M][K], Bh/Bl [N][K] bf16 bits in ushort.
// MODE 0: QKV head-major demux -> C0=q[32][S][64], C1=k[8][S][64], C2=v.
// MODE 1: row-major C0[m][ldc] += ... (out projection).
// ---------------------------------------------------------------------------
template <int MODE>
__global__ __launch_bounds__(256) void mfma_gemm(
    const ushort* __restrict__ Ah, const ushort* __restrict__ Al,
    const ushort* __restrict__ Bh, const ushort* __restrict__ Bl,
    float* __restrict__ C0, float* __restrict__ C1, float* __restrict__ C2,
    int ldc)
{
    __shared__ ushort sAh[64 * 32], sAl[64 * 32];
    __shared__ ushort sBh[128 * 32], sBl[128 * 32];

    const int t = threadIdx.x;
    const int m0 = blockIdx.x * 64;
    const int n0 = blockIdx.y * 128;

    // staging source base addresses (k advances per step)
    const int srow = t >> 2;            // 0..63
    const int skc = (t & 3) << 3;       // k element offset 0/8/16/24
    const ushort* aH = Ah + (size_t)(m0 + srow) * HIDDEN + skc;
    const ushort* aL = Al + (size_t)(m0 + srow) * HIDDEN + skc;
    const ushort* bH0 = Bh + (size_t)(n0 + srow) * HIDDEN + skc;
    const ushort* bH1 = Bh + (size_t)(n0 + 64 + srow) * HIDDEN + skc;
    const ushort* bL0 = Bl + (size_t)(n0 + srow) * HIDDEN + skc;
    const ushort* bL1 = Bl + (size_t)(n0 + 64 + srow) * HIDDEN + skc;
    ushort* dA_h = sAh + t * 8;  // byte offset t*16: linear in lane order
    ushort* dA_l = sAl + t * 8;
    ushort* dB_h0 = sBh + t * 8;
    ushort* dB_h1 = sBh + 64 * 32 + t * 8;
    ushort* dB_l0 = sBl + t * 8;
    ushort* dB_l1 = sBl + 64 * 32 + t * 8;

    const int lane = t & 63, w = t >> 6;
    const int fr = lane & 15;       // row/col within fragment
    const int fk = lane >> 4;       // k-group (8 elems each)

    f32x4 acc[4][2];
#pragma unroll
    for (int i = 0; i < 4; i++)
#pragma unroll
        for (int j = 0; j < 2; j++) acc[i][j] = {0.f, 0.f, 0.f, 0.f};

    for (int k0 = 0; k0 < HIDDEN; k0 += 32) {
        __syncthreads();  // previous compute done reading LDS
        gload16(aH + k0, dA_h);
        gload16(aL + k0, dA_l);
        gload16(bH0 + k0, dB_h0);
        gload16(bH1 + k0, dB_h1);
        gload16(bL0 + k0, dB_l0);
        gload16(bL1 + k0, dB_l1);
        __syncthreads();  // vmcnt(0)+barrier emitted by compiler

        bf16x8 ah[4], al[4], bh[2], bl[2];
#pragma unroll
        for (int fi = 0; fi < 4; fi++) {
            ah[fi] = *(const bf16x8*)&sAh[(fi * 16 + fr) * 32 + fk * 8];
            al[fi] = *(const bf16x8*)&sAl[(fi * 16 + fr) * 32 + fk * 8];
        }
#pragma unroll
        for (int fj = 0; fj < 2; fj++) {
            bh[fj] = *(const bf16x8*)&sBh[(w * 32 + fj * 16 + fr) * 32 + fk * 8];
            bl[fj] = *(const bf16x8*)&sBl[(w * 32 + fj * 16 + fr) * 32 + fk * 8];
        }
#pragma unroll
        for (int fi = 0; fi < 4; fi++)
#pragma unroll
            for (int fj = 0; fj < 2; fj++) {
                acc[fi][fj] = __builtin_amdgcn_mfma_f32_16x16x32_bf16(
                    ah[fi], bh[fj], acc[fi][fj], 0, 0, 0);
                acc[fi][fj] = __builtin_amdgcn_mfma_f32_16x16x32_bf16(
                    ah[fi], bl[fj], acc[fi][fj], 0, 0, 0);
                acc[fi][fj] = __builtin_amdgcn_mfma_f32_16x16x32_bf16(
                    al[fi], bh[fj], acc[fi][fj], 0, 0, 0);
            }
    }

    // epilogue: C/D layout col=lane&15, row=(lane>>4)*4+reg
#pragma unroll
    for (int fi = 0; fi < 4; fi++)
#pragma unroll
        for (int fj = 0; fj < 2; fj++) {
            int row0 = m0 + fi * 16 + fk * 4;
            int gcol = n0 + w * 32 + fj * 16 + fr;
            if (MODE == 0) {
                int slot = gcol >> 6, cin = gcol & 63;
                float* dst;
                if (slot < NH) dst = C0 + (size_t)slot * S_LEN * HD;
                else if (slot < NH + NKV) dst = C1 + (size_t)(slot - NH) * S_LEN * HD;
                else dst = C2 + (size_t)(slot - NH - NKV) * S_LEN * HD;
#pragma unroll
                for (int i = 0; i < 4; i++)
                    dst[(size_t)(row0 + i) * HD + cin] = acc[fi][fj][i];
            } else {
#pragma unroll
                for (int i = 0; i < 4; i++)
                    C0[(size_t)(row0 + i) * ldc + gcol] = acc[fi][fj][i];
            }
        }
}

// ---------------------------------------------------------------------------
// In-place RoPE on Q ([NH][S][HD]) and K ([NKV][S][HD]).
// ---------------------------------------------------------------------------
__global__ __launch_bounds__(256) void rope_kernel(
    float* __restrict__ q, float* __restrict__ k,
    const float* __restrict__ cosT, const float* __restrict__ sinT)
{
    int idx = blockIdx.x * 256 + threadIdx.x;  // (NH+NKV)*S*32 exact
    int d = idx & 31;
    int s = (idx >> 5) & (S_LEN - 1);
    int slot = idx >> 16;
    float* base = (slot < NH) ? (q + ((long)slot * S_LEN + s) * HD)
                              : (k + ((long)(slot - NH) * S_LEN + s) * HD);
    float c = cosT[s * HD + d];
    float sn = sinT[s * HD + d];
    float x1 = base[d], x2 = base[d + 32];
    base[d]      = x1 * c - x2 * sn;
    base[d + 32] = x2 * c + x1 * sn;
}

// ---------------------------------------------------------------------------
// Flash causal attention (fp32, unchanged this round).
// ---------------------------------------------------------------------------
__global__ __launch_bounds__(256) void attn_kernel(
    const float* __restrict__ Qw, const float* __restrict__ Kw,
    const float* __restrict__ Vw, float* __restrict__ Ow)
{
    __shared__ float Qs[64][68];
    __shared__ float KVs[64][68];
    __shared__ float Ss[64][68];
    __shared__ float m_run[64], l_run[64], corr_s[64];

    const int tid = threadIdx.x;
    const int h = blockIdx.y;
    const int hk = h >> 2;
    const int qt = blockIdx.x;
    const int q0 = qt * 64;
    const float* Qb = Qw + ((long)h * S_LEN + q0) * HD;
    const float* Kb = Kw + (long)hk * S_LEN * HD;
    const float* Vb = Vw + (long)hk * S_LEN * HD;
    const int tx = tid & 15, ty = tid >> 4;

#pragma unroll
    for (int p = 0; p < 4; p++) {
        int pos = tid + p * 256;
        int row = pos >> 4, c4 = pos & 15;
        float4 v = *(const float4*)(Qb + row * HD + c4 * 4);
        Qs[c4 * 4 + 0][row] = v.x; Qs[c4 * 4 + 1][row] = v.y;
        Qs[c4 * 4 + 2][row] = v.z; Qs[c4 * 4 + 3][row] = v.w;
    }
    if (tid < 64) { m_run[tid] = -1e30f; l_run[tid] = 0.f; }

    float accO[4][4];
#pragma unroll
    for (int i = 0; i < 4; i++)
#pragma unroll
        for (int j = 0; j < 4; j++) accO[i][j] = 0.f;

    const int lane = tid & 63, w = tid >> 6;
    const int r = lane >> 2, jj = lane & 3;
    const int srow = w * 16 + r;

    for (int t = 0; t <= qt; t++) {
        const int k0 = t * 64;
        __syncthreads();
#pragma unroll
        for (int p = 0; p < 4; p++) {
            int pos = tid + p * 256;
            int row = pos >> 4, c4 = pos & 15;
            float4 v = *(const float4*)(Kb + (long)(k0 + row) * HD + c4 * 4);
            KVs[c4 * 4 + 0][row] = v.x; KVs[c4 * 4 + 1][row] = v.y;
            KVs[c4 * 4 + 2][row] = v.z; KVs[c4 * 4 + 3][row] = v.w;
        }
        __syncthreads();
        float sc[4][4];
#pragma unroll
        for (int i = 0; i < 4; i++)
#pragma unroll
            for (int j = 0; j < 4; j++) sc[i][j] = 0.f;
#pragma unroll 8
        for (int d = 0; d < 64; d++) {
            float a[4], b[4];
            *(float4*)a = *(const float4*)&Qs[d][ty * 4];
            *(float4*)b = *(const float4*)&KVs[d][tx * 4];
#pragma unroll
            for (int i = 0; i < 4; i++)
#pragma unroll
                for (int j = 0; j < 4; j++)
                    sc[i][j] = fmaf(a[i], b[j], sc[i][j]);
        }
        const bool diag = (t == qt);
#pragma unroll
        for (int i = 0; i < 4; i++) {
            float4 o;
            float* po = &o.x;
#pragma unroll
            for (int j = 0; j < 4; j++) {
                float s = sc[i][j] * SCALE;
                if (diag && (tx * 4 + j) > (ty * 4 + i)) s = -1e30f;
                po[j] = s;
            }
            *(float4*)&Ss[ty * 4 + i][tx * 4] = o;
        }
        __syncthreads();

        float4 vr[4];
#pragma unroll
        for (int p = 0; p < 4; p++) {
            int pos = tid + p * 256;
            int row = pos >> 4, c4 = pos & 15;
            vr[p] = *(const float4*)(Vb + (long)(k0 + row) * HD + c4 * 4);
        }
        float mx = -1e30f;
#pragma unroll
        for (int c = 0; c < 16; c++) mx = fmaxf(mx, Ss[srow][jj * 16 + c]);
        mx = fmaxf(mx, __shfl_xor(mx, 1));
        mx = fmaxf(mx, __shfl_xor(mx, 2));
        float mold = m_run[srow];
        float mnew = fmaxf(mold, mx);
        float corr = __expf(mold - mnew);
        float sum = 0.f;
#pragma unroll
        for (int c = 0; c < 16; c++) {
            float pv = __expf(Ss[srow][jj * 16 + c] - mnew);
            Ss[srow][jj * 16 + c] = pv;
            sum += pv;
        }
        sum += __shfl_xor(sum, 1);
        sum += __shfl_xor(sum, 2);
        if (jj == 0) {
            m_run[srow] = mnew;
            l_run[srow] = l_run[srow] * corr + sum;
            corr_s[srow] = corr;
        }
#pragma unroll
        for (int p = 0; p < 4; p++) {
            int pos = tid + p * 256;
            int row = pos >> 4, c4 = pos & 15;
            *(float4*)&KVs[row][c4 * 4] = vr[p];
        }
        __syncthreads();
#pragma unroll
        for (int i = 0; i < 4; i++) {
            float cr = corr_s[ty * 4 + i];
#pragma unroll
            for (int j = 0; j < 4; j++) accO[i][j] *= cr;
        }
#pragma unroll 8
        for (int n = 0; n < 64; n++) {
            float b[4];
            *(float4*)b = *(const float4*)&KVs[n][tx * 4];
#pragma unroll
            for (int i = 0; i < 4; i++) {
                float pp = Ss[ty * 4 + i][n];
#pragma unroll
                for (int j = 0; j < 4; j++)
                    accO[i][j] = fmaf(pp, b[j], accO[i][j]);
            }
        }
    }
#pragma unroll
    for (int i = 0; i < 4; i++) {
        float inv = 1.0f / l_run[ty * 4 + i];
        float4 o;
        o.x = accO[i][0] * inv; o.y = accO[i][1] * inv;
        o.z = accO[i][2] * inv; o.w = accO[i][3] * inv;
        *(float4*)(Ow + (long)(q0 + ty * 4 + i) * (NH * HD) + h * HD + tx * 4) = o;
    }
}

// ---------------------------------------------------------------------------
extern "C" void kernel_launch(void* const* d_in, const int* in_sizes, int n_in,
                              void* d_out, int out_size, void* d_ws, size_t ws_size,
                              hipStream_t stream) {
    const float* hidden = (const float*)d_in[0];
    const float* cosT   = (const float*)d_in[1];
    const float* sinT   = (const float*)d_in[2];
    // d_in[3] = attention_mask: exactly causal -> analytic
    const float* wq = (const float*)d_in[4];
    const float* wk = (const float*)d_in[5];
    const float* wv = (const float*)d_in[6];
    const float* wo = (const float*)d_in[7];
    float* out = (float*)d_out;

    // workspace layout
    char* wsb = (char*)d_ws;
    auto alloc = [&](size_t bytes) { char* p = wsb; wsb += (bytes + 255) & ~255ULL; return p; };
    float* q = (float*)alloc((size_t)NH * S_LEN * HD * 4);      // 16.8 MB
    float* k = (float*)alloc((size_t)NKV * S_LEN * HD * 4);     //  4.2 MB
    float* v = (float*)alloc((size_t)NKV * S_LEN * HD * 4);     //  4.2 MB
    float* o = (float*)alloc((size_t)S_LEN * NH * HD * 4);      // 16.8 MB
    ushort* hidH = (ushort*)alloc((size_t)S_LEN * HIDDEN * 2);  //  8.4 MB
    ushort* hidL = (ushort*)alloc((size_t)S_LEN * HIDDEN * 2);
    ushort* WcH  = (ushort*)alloc((size_t)3072 * HIDDEN * 2);   // 12.6 MB (wq|wk|wv)
    ushort* WcL  = (ushort*)alloc((size_t)3072 * HIDDEN * 2);
    ushort* woH  = (ushort*)alloc((size_t)HIDDEN * 2048 * 2);
    ushort* woL  = (ushort*)alloc((size_t)HIDDEN * 2048 * 2);
    ushort* oH   = (ushort*)alloc((size_t)S_LEN * 2048 * 2);
    ushort* oL   = (ushort*)alloc((size_t)S_LEN * 2048 * 2);

    dim3 blk(256);
    // splits
    {
        int n4 = S_LEN * HIDDEN / 4;
        split_bf16<<<(n4 + 255) / 256, blk, 0, stream>>>(hidden, hidH, hidL, n4);
        int nq4 = NH * HD * HIDDEN / 4;
        split_bf16<<<(nq4 + 255) / 256, blk, 0, stream>>>(wq, WcH, WcL, nq4);
        int nk4 = NKV * HD * HIDDEN / 4;
        size_t off = (size_t)NH * HD * HIDDEN;
        split_bf16<<<(nk4 + 255) / 256, blk, 0, stream>>>(wk, WcH + off, WcL + off, nk4);
        size_t off2 = off + (size_t)NKV * HD * HIDDEN;
        split_bf16<<<(nk4 + 255) / 256, blk, 0, stream>>>(wv, WcH + off2, WcL + off2, nk4);
        int nw4 = HIDDEN * 2048 / 4;
        split_bf16<<<(nw4 + 255) / 256, blk, 0, stream>>>(wo, woH, woL, nw4);
    }
    // QKV projection: M=2048, N=3072
    mfma_gemm<0><<<dim3(S_LEN / 64, 3072 / 128), blk, 0, stream>>>(
        hidH, hidL, WcH, WcL, q, k, v, 0);
    // RoPE in place
    rope_kernel<<<(NH + NKV) * S_LEN * 32 / 256, blk, 0, stream>>>(q, k, cosT, sinT);
    // attention
    attn_kernel<<<dim3(S_LEN / 64, NH), blk, 0, stream>>>(q, k, v, o);
    // split attention output, then out projection: M=2048, N=2048
    {
        int n4 = S_LEN * 2048 / 4;
        split_bf16<<<(n4 + 255) / 256, blk, 0, stream>>>(o, oH, oL, n4);
    }
    mfma_gemm<1><<<dim3(S_LEN / 64, 2048 / 128), blk, 0, stream>>>(
        oH, oL, woH, woL, out, nullptr, nullptr, 2048);
}

// Round 3
// 417.098 us; speedup vs baseline: 3.2659x; 1.8482x over previous
//
#include <hip/hip_runtime.h>
#include <hip/hip_bf16.h>
#include <stdint.h>

// Fused GQA attention layer.
// Round 3: MFMA flash attention (split-bf16 QK^T, bf16 P x split V), with
// pre-split/pre-swizzled K and V^T planes staged via global_load_lds.

#define S_LEN 2048
#define HIDDEN 2048
#define NH 32
#define NKV 8
#define HD 64
#define SCALE 0.125f

typedef __bf16 bf16x8 __attribute__((ext_vector_type(8)));
typedef float f32x4 __attribute__((ext_vector_type(4)));
typedef float f32x16 __attribute__((ext_vector_type(16)));

__device__ inline void gload16(const void* g, void* l) {
    using GP = const __attribute__((address_space(1))) uint32_t*;
    using LP = __attribute__((address_space(3))) uint32_t*;
    __builtin_amdgcn_global_load_lds((GP)g, (LP)(uint32_t)(uintptr_t)l, 16, 0, 0);
}

__device__ inline ushort bf16r(float x) {
    uint32_t u = __float_as_uint(x);
    return (ushort)((u + 0x7FFFu + ((u >> 16) & 1u)) >> 16);
}
__device__ inline void bsplit(float x, ushort& h, ushort& l) {
    uint32_t u = __float_as_uint(x);
    uint32_t hr = (u + 0x7FFFu + ((u >> 16) & 1u)) >> 16;
    float r = x - __uint_as_float(hr << 16);
    uint32_t ul = __float_as_uint(r);
    l = (ushort)((ul + 0x7FFFu + ((ul >> 16) & 1u)) >> 16);
    h = (ushort)hr;
}

// ---------------------------------------------------------------------------
// fp32 -> (bf16 hi, bf16 lo) planes, vectorized x4.
// ---------------------------------------------------------------------------
__global__ __launch_bounds__(256) void split_bf16(
    const float* __restrict__ src, ushort* __restrict__ hi,
    ushort* __restrict__ lo, int n4)
{
    int i = blockIdx.x * 256 + threadIdx.x;
    if (i >= n4) return;
    float4 v = ((const float4*)src)[i];
    float x[4] = {v.x, v.y, v.z, v.w};
    ushort h[4], l[4];
#pragma unroll
    for (int j = 0; j < 4; j++) bsplit(x[j], h[j], l[j]);
    ushort4 ho = {h[0], h[1], h[2], h[3]};
    ushort4 lv = {l[0], l[1], l[2], l[3]};
    ((ushort4*)hi)[i] = ho;
    ((ushort4*)lo)[i] = lv;
}

// ---------------------------------------------------------------------------
// Split-bf16 MFMA GEMM (unchanged from round 2).
// ---------------------------------------------------------------------------
template <int MODE>
__global__ __launch_bounds__(256) void mfma_gemm(
    const ushort* __restrict__ Ah, const ushort* __restrict__ Al,
    const ushort* __restrict__ Bh, const ushort* __restrict__ Bl,
    float* __restrict__ C0, float* __restrict__ C1, float* __restrict__ C2,
    int ldc)
{
    __shared__ ushort sAh[64 * 32], sAl[64 * 32];
    __shared__ ushort sBh[128 * 32], sBl[128 * 32];

    const int t = threadIdx.x;
    const int m0 = blockIdx.x * 64;
    const int n0 = blockIdx.y * 128;

    const int srow = t >> 2;
    const int skc = (t & 3) << 3;
    const ushort* aH = Ah + (size_t)(m0 + srow) * HIDDEN + skc;
    const ushort* aL = Al + (size_t)(m0 + srow) * HIDDEN + skc;
    const ushort* bH0 = Bh + (size_t)(n0 + srow) * HIDDEN + skc;
    const ushort* bH1 = Bh + (size_t)(n0 + 64 + srow) * HIDDEN + skc;
    const ushort* bL0 = Bl + (size_t)(n0 + srow) * HIDDEN + skc;
    const ushort* bL1 = Bl + (size_t)(n0 + 64 + srow) * HIDDEN + skc;
    ushort* dA_h = sAh + t * 8;
    ushort* dA_l = sAl + t * 8;
    ushort* dB_h0 = sBh + t * 8;
    ushort* dB_h1 = sBh + 64 * 32 + t * 8;
    ushort* dB_l0 = sBl + t * 8;
    ushort* dB_l1 = sBl + 64 * 32 + t * 8;

    const int lane = t & 63, w = t >> 6;
    const int fr = lane & 15;
    const int fk = lane >> 4;

    f32x4 acc[4][2];
#pragma unroll
    for (int i = 0; i < 4; i++)
#pragma unroll
        for (int j = 0; j < 2; j++) acc[i][j] = {0.f, 0.f, 0.f, 0.f};

    for (int k0 = 0; k0 < HIDDEN; k0 += 32) {
        __syncthreads();
        gload16(aH + k0, dA_h);
        gload16(aL + k0, dA_l);
        gload16(bH0 + k0, dB_h0);
        gload16(bH1 + k0, dB_h1);
        gload16(bL0 + k0, dB_l0);
        gload16(bL1 + k0, dB_l1);
        __syncthreads();

        bf16x8 ah[4], al[4], bh[2], bl[2];
#pragma unroll
        for (int fi = 0; fi < 4; fi++) {
            ah[fi] = *(const bf16x8*)&sAh[(fi * 16 + fr) * 32 + fk * 8];
            al[fi] = *(const bf16x8*)&sAl[(fi * 16 + fr) * 32 + fk * 8];
        }
#pragma unroll
        for (int fj = 0; fj < 2; fj++) {
            bh[fj] = *(const bf16x8*)&sBh[(w * 32 + fj * 16 + fr) * 32 + fk * 8];
            bl[fj] = *(const bf16x8*)&sBl[(w * 32 + fj * 16 + fr) * 32 + fk * 8];
        }
#pragma unroll
        for (int fi = 0; fi < 4; fi++)
#pragma unroll
            for (int fj = 0; fj < 2; fj++) {
                acc[fi][fj] = __builtin_amdgcn_mfma_f32_16x16x32_bf16(
                    ah[fi], bh[fj], acc[fi][fj], 0, 0, 0);
                acc[fi][fj] = __builtin_amdgcn_mfma_f32_16x16x32_bf16(
                    ah[fi], bl[fj], acc[fi][fj], 0, 0, 0);
                acc[fi][fj] = __builtin_amdgcn_mfma_f32_16x16x32_bf16(
                    al[fi], bh[fj], acc[fi][fj], 0, 0, 0);
            }
    }

#pragma unroll
    for (int fi = 0; fi < 4; fi++)
#pragma unroll
        for (int fj = 0; fj < 2; fj++) {
            int row0 = m0 + fi * 16 + fk * 4;
            int gcol = n0 + w * 32 + fj * 16 + fr;
            if (MODE == 0) {
                int slot = gcol >> 6, cin = gcol & 63;
                float* dst;
                if (slot < NH) dst = C0 + (size_t)slot * S_LEN * HD;
                else if (slot < NH + NKV) dst = C1 + (size_t)(slot - NH) * S_LEN * HD;
                else dst = C2 + (size_t)(slot - NH - NKV) * S_LEN * HD;
#pragma unroll
                for (int i = 0; i < 4; i++)
                    dst[(size_t)(row0 + i) * HD + cin] = acc[fi][fj][i];
            } else {
#pragma unroll
                for (int i = 0; i < 4; i++)
                    C0[(size_t)(row0 + i) * ldc + gcol] = acc[fi][fj][i];
            }
        }
}

// ---------------------------------------------------------------------------
// RoPE: q in-place fp32; k -> rope'd, split hi/lo, XOR-swizzled bf16 planes.
// khi/klo layout [NKV][S][64], element (s,d) stored at col d ^ ((s&7)<<3).
// ---------------------------------------------------------------------------
__global__ __launch_bounds__(256) void rope_split(
    float* __restrict__ qd, const float* __restrict__ kd,
    const float* __restrict__ cosT, const float* __restrict__ sinT,
    ushort* __restrict__ khi, ushort* __restrict__ klo)
{
    int idx = blockIdx.x * 256 + threadIdx.x;  // (NH+NKV)*S*32 exact
    int d = idx & 31;
    int s = (idx >> 5) & (S_LEN - 1);
    int slot = idx >> 16;
    float c = cosT[s * HD + d];
    float sn = sinT[s * HD + d];
    if (slot < NH) {
        float* base = qd + ((size_t)slot * S_LEN + s) * HD;
        float x1 = base[d], x2 = base[d + 32];
        base[d] = x1 * c - x2 * sn;
        base[d + 32] = x2 * c + x1 * sn;
    } else {
        const float* base = kd + ((size_t)(slot - NH) * S_LEN + s) * HD;
        float x1 = base[d], x2 = base[d + 32];
        float y1 = x1 * c - x2 * sn;
        float y2 = x2 * c + x1 * sn;
        int sw = (s & 7) << 3;
        size_t rb = ((size_t)(slot - NH) * S_LEN + s) * 64;
        ushort h1, l1, h2, l2;
        bsplit(y1, h1, l1);
        bsplit(y2, h2, l2);
        khi[rb + (d ^ sw)] = h1;        klo[rb + (d ^ sw)] = l1;
        khi[rb + ((d + 32) ^ sw)] = h2; klo[rb + ((d + 32) ^ sw)] = l2;
    }
}

// ---------------------------------------------------------------------------
// V -> V^T split planes, swizzled. vthi/vtlo [NKV][64 d][S keys],
// element (d,key) stored at key-low-6 position (key&63) ^ ((d&7)<<3).
// One block per 64x64 tile.
// ---------------------------------------------------------------------------
__global__ __launch_bounds__(256) void split_vt(
    const float* __restrict__ v, ushort* __restrict__ vthi,
    ushort* __restrict__ vtlo)
{
    __shared__ float tile[64][65];
    const int b = blockIdx.x;          // NKV * S/64
    const int hk = b >> 5, kt = b & 31;
    const float* src = v + ((size_t)hk * S_LEN + kt * 64) * 64;
    const int t = threadIdx.x;
    {
        int row = t >> 2, dg = (t & 3) * 16;
#pragma unroll
        for (int i = 0; i < 4; i++) {
            float4 x = *(const float4*)(src + row * 64 + dg + i * 4);
            tile[row][dg + i * 4 + 0] = x.x;
            tile[row][dg + i * 4 + 1] = x.y;
            tile[row][dg + i * 4 + 2] = x.z;
            tile[row][dg + i * 4 + 3] = x.w;
        }
    }
    __syncthreads();
    const int d = t >> 2, kg = (t & 3) * 16;
    ushort hi16[16], lo16[16];
#pragma unroll
    for (int i = 0; i < 16; i++) bsplit(tile[kg + i][d], hi16[i], lo16[i]);
    const int sw = (d & 7) << 3;
    size_t rowb = ((size_t)hk * 64 + d) * S_LEN + kt * 64;
    int base = kg ^ (sw & 48);
    int o0 = base + (sw & 8);        // keys kg+0..7
    int o1 = base + (8 ^ (sw & 8));  // keys kg+8..15
    *(ushort4*)&vthi[rowb + o0]     = *(ushort4*)&hi16[0];
    *(ushort4*)&vthi[rowb + o0 + 4] = *(ushort4*)&hi16[4];
    *(ushort4*)&vthi[rowb + o1]     = *(ushort4*)&hi16[8];
    *(ushort4*)&vthi[rowb + o1 + 4] = *(ushort4*)&hi16[12];
    *(ushort4*)&vtlo[rowb + o0]     = *(ushort4*)&lo16[0];
    *(ushort4*)&vtlo[rowb + o0 + 4] = *(ushort4*)&lo16[4];
    *(ushort4*)&vtlo[rowb + o1]     = *(ushort4*)&lo16[8];
    *(ushort4*)&vtlo[rowb + o1 + 4] = *(ushort4*)&lo16[12];
}

// ---------------------------------------------------------------------------
// MFMA flash attention. Grid (16 q-blocks, 32 heads), 256 threads (4 waves).
// QBLK=128 (wave w owns queries w*32..+31), KVBLK=64.
// Swapped QK^T: S^T = K.Q^T via mfma_f32_32x32x16_bf16, so softmax reduction
// is in-lane + shfl_xor(32). P -> wave-private LDS -> PV mfma.
// ---------------------------------------------------------------------------
__global__ __launch_bounds__(256) void attn_mfma(
    const float* __restrict__ q,
    const ushort* __restrict__ khi, const ushort* __restrict__ klo,
    const ushort* __restrict__ vthi, const ushort* __restrict__ vtlo,
    float* __restrict__ o)
{
    __shared__ ushort uni[16384];      // 32KB: Q-stage, then Khi|Klo|Vth|Vtl (8KB each)
    __shared__ ushort Pl[4][32 * 72];  // per-wave P, padded stride 72
    __shared__ float corrw[4][32];
    __shared__ float lw[4][32];

    const int t = threadIdx.x;
    const int lane = t & 63, w = t >> 6;
    const int h = blockIdx.y, hk = h >> 2;
    const int qt = (int)gridDim.x - 1 - (int)blockIdx.x;  // heavy blocks first
    const int q0 = qt * 128;
    const int l31 = lane & 31;
    const int dh = (lane >> 5) * 8;

    // ---- stage Q tile (fp32 -> hi/lo, swizzled) ----
    {
        const int row = t >> 1, dg = (t & 1) * 32;
        const float* src = q + ((size_t)h * S_LEN + q0 + row) * HD + dg;
        const int sw = (row & 7) << 3;
#pragma unroll
        for (int i = 0; i < 8; i++) {
            float4 v4 = *(const float4*)(src + i * 4);
            float xs[4] = {v4.x, v4.y, v4.z, v4.w};
            ushort h4[4], l4[4];
#pragma unroll
            for (int j = 0; j < 4; j++) bsplit(xs[j], h4[j], l4[j]);
            int idx = (row * 64 + dg + i * 4) ^ sw;
            *(ushort4*)&uni[idx] = *(ushort4*)&h4[0];
            *(ushort4*)&uni[8192 + idx] = *(ushort4*)&l4[0];
        }
    }
    __syncthreads();
    // ---- Q fragments to registers ----
    bf16x8 qh[4], ql[4];
    {
        const int qrow = w * 32 + l31;
        const int sw = (qrow & 7) << 3;
#pragma unroll
        for (int ks = 0; ks < 4; ks++) {
            int idx = (qrow * 64 + ks * 16 + dh) ^ sw;
            qh[ks] = *(const bf16x8*)&uni[idx];
            ql[ks] = *(const bf16x8*)&uni[8192 + idx];
        }
    }

    f32x16 accO0, accO1;
#pragma unroll
    for (int r = 0; r < 16; r++) { accO0[r] = 0.f; accO1[r] = 0.f; }
    float m_run = -1e30f, l_run = 0.f;

    const ushort* khi_t = khi + (size_t)hk * S_LEN * 64;
    const ushort* klo_t = klo + (size_t)hk * S_LEN * 64;
    const ushort* vth_t = vthi + (size_t)hk * 64 * S_LEN;
    const ushort* vtl_t = vtlo + (size_t)hk * 64 * S_LEN;
    ushort* Pw = &Pl[w][0];
    const int swk = (l31 & 7) << 3;
    const int qg = q0 + w * 32 + l31;
    const int d0s = t >> 3, kks = (t & 7) * 8;  // Vt staging coords

    const int ntiles = 2 * qt + 2;
    for (int tile = 0; tile < ntiles; tile++) {
        const int k0 = tile * 64;
        __syncthreads();  // previous tile fully consumed
        {
            const ushort* a = khi_t + k0 * 64;
            const ushort* b = klo_t + k0 * 64;
            gload16(a + t * 8, &uni[t * 8]);
            gload16(a + 2048 + t * 8, &uni[2048 + t * 8]);
            gload16(b + t * 8, &uni[4096 + t * 8]);
            gload16(b + 2048 + t * 8, &uni[6144 + t * 8]);
            gload16(vth_t + (size_t)d0s * S_LEN + k0 + kks, &uni[8192 + t * 8]);
            gload16(vth_t + (size_t)(d0s + 32) * S_LEN + k0 + kks, &uni[10240 + t * 8]);
            gload16(vtl_t + (size_t)d0s * S_LEN + k0 + kks, &uni[12288 + t * 8]);
            gload16(vtl_t + (size_t)(d0s + 32) * S_LEN + k0 + kks, &uni[14336 + t * 8]);
        }
        __syncthreads();  // vmcnt(0) drained before barrier

        // ---- scores S^T[key][query] ----
        f32x16 sc0, sc1;
#pragma unroll
        for (int r = 0; r < 16; r++) { sc0[r] = 0.f; sc1[r] = 0.f; }
#pragma unroll
        for (int ks = 0; ks < 4; ks++) {
            int off = ks * 16 + dh;
            int i0 = (l31 * 64 + off) ^ swk;
            int i1 = ((l31 + 32) * 64 + off) ^ swk;
            bf16x8 kh0 = *(const bf16x8*)&uni[i0];
            bf16x8 kl0 = *(const bf16x8*)&uni[4096 + i0];
            bf16x8 kh1 = *(const bf16x8*)&uni[i1];
            bf16x8 kl1 = *(const bf16x8*)&uni[4096 + i1];
            sc0 = __builtin_amdgcn_mfma_f32_32x32x16_bf16(kh0, qh[ks], sc0, 0, 0, 0);
            sc1 = __builtin_amdgcn_mfma_f32_32x32x16_bf16(kh1, qh[ks], sc1, 0, 0, 0);
            sc0 = __builtin_amdgcn_mfma_f32_32x32x16_bf16(kh0, ql[ks], sc0, 0, 0, 0);
            sc1 = __builtin_amdgcn_mfma_f32_32x32x16_bf16(kh1, ql[ks], sc1, 0, 0, 0);
            sc0 = __builtin_amdgcn_mfma_f32_32x32x16_bf16(kl0, qh[ks], sc0, 0, 0, 0);
            sc1 = __builtin_amdgcn_mfma_f32_32x32x16_bf16(kl1, qh[ks], sc1, 0, 0, 0);
        }

        // ---- mask + scale + online softmax (query = l31, keys in regs) ----
        const bool maskt = (tile >= 2 * qt);
        float mx = -1e30f;
#pragma unroll
        for (int r = 0; r < 16; r++) {
            int krow = (r & 3) + 8 * (r >> 2) + 4 * (lane >> 5);
            float v0 = sc0[r] * SCALE;
            float v1 = sc1[r] * SCALE;
            if (maskt) {
                if (k0 + krow > qg) v0 = -1e30f;
                if (k0 + 32 + krow > qg) v1 = -1e30f;
            }
            sc0[r] = v0; sc1[r] = v1;
            mx = fmaxf(mx, fmaxf(v0, v1));
        }
        mx = fmaxf(mx, __shfl_xor(mx, 32));

        float corr = 1.f;
        const bool skip = __all(mx - m_run <= 8.0f);
        if (!skip) {
            float m_new = fmaxf(m_run, mx);
            corr = __expf(m_run - m_new);
            m_run = m_new;
            if (lane < 32) corrw[w][l31] = corr;
        }
        float sum = 0.f;
#pragma unroll
        for (int r = 0; r < 16; r++) {
            float p0 = __expf(sc0[r] - m_run);
            float p1 = __expf(sc1[r] - m_run);
            sc0[r] = p0; sc1[r] = p1;
            sum += p0 + p1;
        }
        sum += __shfl_xor(sum, 32);
        l_run = l_run * corr + sum;

        // ---- P -> wave-private LDS (bf16) ----
#pragma unroll
        for (int r = 0; r < 16; r += 2) {
            int krow = (r & 3) + 8 * (r >> 2) + 4 * (lane >> 5);
            uint32_t b0 = (uint32_t)bf16r(sc0[r]) | ((uint32_t)bf16r(sc0[r + 1]) << 16);
            uint32_t b1 = (uint32_t)bf16r(sc1[r]) | ((uint32_t)bf16r(sc1[r + 1]) << 16);
            *(uint32_t*)&Pw[l31 * 72 + krow] = b0;
            *(uint32_t*)&Pw[l31 * 72 + 32 + krow] = b1;
        }

        // ---- rescale accumulator (rare: defer-max) ----
        if (!skip) {
#pragma unroll
            for (int r = 0; r < 16; r++) {
                int qrow = (r & 3) + 8 * (r >> 2) + 4 * (lane >> 5);
                float cr = corrw[w][qrow];
                accO0[r] *= cr; accO1[r] *= cr;
            }
        }

        // ---- PV: O[q][d] += P.V ----
#pragma unroll
        for (int ks = 0; ks < 4; ks++) {
            bf16x8 pa = *(const bf16x8*)&Pw[l31 * 72 + ks * 16 + dh];
            int ia = (l31 * 64 + ks * 16 + dh) ^ swk;
            int ib = ((l31 + 32) * 64 + ks * 16 + dh) ^ swk;
            bf16x8 vh0 = *(const bf16x8*)&uni[8192 + ia];
            bf16x8 vh1 = *(const bf16x8*)&uni[8192 + ib];
            bf16x8 vl0 = *(const bf16x8*)&uni[12288 + ia];
            bf16x8 vl1 = *(const bf16x8*)&uni[12288 + ib];
            accO0 = __builtin_amdgcn_mfma_f32_32x32x16_bf16(pa, vh0, accO0, 0, 0, 0);
            accO1 = __builtin_amdgcn_mfma_f32_32x32x16_bf16(pa, vh1, accO1, 0, 0, 0);
            accO0 = __builtin_amdgcn_mfma_f32_32x32x16_bf16(pa, vl0, accO0, 0, 0, 0);
            accO1 = __builtin_amdgcn_mfma_f32_32x32x16_bf16(pa, vl1, accO1, 0, 0, 0);
        }
    }

    // ---- epilogue: O / l ----
    if (lane < 32) lw[w][l31] = l_run;
#pragma unroll
    for (int r = 0; r < 16; r++) {
        int qrow = (r & 3) + 8 * (r >> 2) + 4 * (lane >> 5);
        float inv = 1.0f / lw[w][qrow];
        float* dst = o + (size_t)(q0 + w * 32 + qrow) * (NH * HD) + h * 64;
        dst[l31] = accO0[r] * inv;
        dst[32 + l31] = accO1[r] * inv;
    }
}

// ---------------------------------------------------------------------------
extern "C" void kernel_launch(void* const* d_in, const int* in_sizes, int n_in,
                              void* d_out, int out_size, void* d_ws, size_t ws_size,
                              hipStream_t stream) {
    const float* hidden = (const float*)d_in[0];
    const float* cosT   = (const float*)d_in[1];
    const float* sinT   = (const float*)d_in[2];
    // d_in[3] = attention_mask: exactly causal -> analytic
    const float* wq = (const float*)d_in[4];
    const float* wk = (const float*)d_in[5];
    const float* wv = (const float*)d_in[6];
    const float* wo = (const float*)d_in[7];
    float* out = (float*)d_out;

    char* wsb = (char*)d_ws;
    auto alloc = [&](size_t bytes) { char* p = wsb; wsb += (bytes + 255) & ~255ULL; return p; };
    float* q = (float*)alloc((size_t)NH * S_LEN * HD * 4);
    float* k = (float*)alloc((size_t)NKV * S_LEN * HD * 4);
    float* v = (float*)alloc((size_t)NKV * S_LEN * HD * 4);
    float* o = (float*)alloc((size_t)S_LEN * NH * HD * 4);
    ushort* hidH = (ushort*)alloc((size_t)S_LEN * HIDDEN * 2);
    ushort* hidL = (ushort*)alloc((size_t)S_LEN * HIDDEN * 2);
    ushort* WcH  = (ushort*)alloc((size_t)3072 * HIDDEN * 2);
    ushort* WcL  = (ushort*)alloc((size_t)3072 * HIDDEN * 2);
    ushort* woH  = (ushort*)alloc((size_t)HIDDEN * 2048 * 2);
    ushort* woL  = (ushort*)alloc((size_t)HIDDEN * 2048 * 2);
    ushort* oH   = (ushort*)alloc((size_t)S_LEN * 2048 * 2);
    ushort* oL   = (ushort*)alloc((size_t)S_LEN * 2048 * 2);
    // K/V planes alias hidH (dead after the QKV GEMM): 4 x 1,048,576 ushorts.
    ushort* khi  = hidH;
    ushort* klo  = hidH + 1048576;
    ushort* vthi = hidH + 2097152;
    ushort* vtlo = hidH + 3145728;

    dim3 blk(256);
    {
        int n4 = S_LEN * HIDDEN / 4;
        split_bf16<<<(n4 + 255) / 256, blk, 0, stream>>>(hidden, hidH, hidL, n4);
        int nq4 = NH * HD * HIDDEN / 4;
        split_bf16<<<(nq4 + 255) / 256, blk, 0, stream>>>(wq, WcH, WcL, nq4);
        int nk4 = NKV * HD * HIDDEN / 4;
        size_t off = (size_t)NH * HD * HIDDEN;
        split_bf16<<<(nk4 + 255) / 256, blk, 0, stream>>>(wk, WcH + off, WcL + off, nk4);
        size_t off2 = off + (size_t)NKV * HD * HIDDEN;
        split_bf16<<<(nk4 + 255) / 256, blk, 0, stream>>>(wv, WcH + off2, WcL + off2, nk4);
        int nw4 = HIDDEN * 2048 / 4;
        split_bf16<<<(nw4 + 255) / 256, blk, 0, stream>>>(wo, woH, woL, nw4);
    }
    // QKV projection
    mfma_gemm<0><<<dim3(S_LEN / 64, 3072 / 128), blk, 0, stream>>>(
        hidH, hidL, WcH, WcL, q, k, v, 0);
    // RoPE (q in place) + K split planes (overwrites hidH region — now dead)
    rope_split<<<(NH + NKV) * S_LEN * 32 / 256, blk, 0, stream>>>(
        q, k, cosT, sinT, khi, klo);
    // V^T split planes
    split_vt<<<NKV * (S_LEN / 64), blk, 0, stream>>>(v, vthi, vtlo);
    // flash attention
    attn_mfma<<<dim3(S_LEN / 128, NH), blk, 0, stream>>>(
        q, khi, klo, vthi, vtlo, o);
    // out projection
    {
        int n4 = S_LEN * 2048 / 4;
        split_bf16<<<(n4 + 255) / 256, blk, 0, stream>>>(o, oH, oL, n4);
    }
    mfma_gemm<1><<<dim3(S_LEN / 64, 2048 / 128), blk, 0, stream>>>(
        oH, oL, woH, woL, out, nullptr, nullptr, 2048);
}

// Round 4
// 405.288 us; speedup vs baseline: 3.3611x; 1.0291x over previous
//
#include <hip/hip_runtime.h>
#include <hip/hip_bf16.h>
#include <stdint.h>

// Fused GQA attention layer.
// Round 4: GEMM LDS row-pair swizzle (conflict-free ds_read_b128 via
// pre-swizzled global_load_lds source addresses), XCD-aware block swizzle,
// attention epilogue writes split planes directly.

#define S_LEN 2048
#define HIDDEN 2048
#define NH 32
#define NKV 8
#define HD 64
#define SCALE 0.125f

typedef __bf16 bf16x8 __attribute__((ext_vector_type(8)));
typedef float f32x4 __attribute__((ext_vector_type(4)));
typedef float f32x16 __attribute__((ext_vector_type(16)));

__device__ inline void gload16(const void* g, void* l) {
    using GP = const __attribute__((address_space(1))) uint32_t*;
    using LP = __attribute__((address_space(3))) uint32_t*;
    __builtin_amdgcn_global_load_lds((GP)g, (LP)(uint32_t)(uintptr_t)l, 16, 0, 0);
}

__device__ inline ushort bf16r(float x) {
    uint32_t u = __float_as_uint(x);
    return (ushort)((u + 0x7FFFu + ((u >> 16) & 1u)) >> 16);
}
__device__ inline void bsplit(float x, ushort& h, ushort& l) {
    uint32_t u = __float_as_uint(x);
    uint32_t hr = (u + 0x7FFFu + ((u >> 16) & 1u)) >> 16;
    float r = x - __uint_as_float(hr << 16);
    uint32_t ul = __float_as_uint(r);
    l = (ushort)((ul + 0x7FFFu + ((ul >> 16) & 1u)) >> 16);
    h = (ushort)hr;
}

// Row-pair swizzled LDS index (ushort units) for a [R][32] bf16 tile:
// line = row>>1 (128B lines, 2 rows each), inner slot = ((fk<<1)|(row&1)) ^ (line&7).
__device__ inline int swz_idx(int row, int fk) {
    int line = row >> 1;
    int inner = (((fk << 1) | (row & 1)) ^ (line & 7));
    return line * 64 + inner * 8;
}

// ---------------------------------------------------------------------------
// fp32 -> (bf16 hi, bf16 lo) planes, vectorized x4.
// ---------------------------------------------------------------------------
__global__ __launch_bounds__(256) void split_bf16(
    const float* __restrict__ src, ushort* __restrict__ hi,
    ushort* __restrict__ lo, int n4)
{
    int i = blockIdx.x * 256 + threadIdx.x;
    if (i >= n4) return;
    float4 v = ((const float4*)src)[i];
    float x[4] = {v.x, v.y, v.z, v.w};
    ushort h[4], l[4];
#pragma unroll
    for (int j = 0; j < 4; j++) bsplit(x[j], h[j], l[j]);
    ushort4 ho = {h[0], h[1], h[2], h[3]};
    ushort4 lv = {l[0], l[1], l[2], l[3]};
    ((ushort4*)hi)[i] = ho;
    ((ushort4*)lo)[i] = lv;
}

// ---------------------------------------------------------------------------
// Split-bf16 MFMA GEMM: C[m][n] = sum_k A[m][k]*Bw[n][k], K = 2048.
// Tile BM=64 x BN=128, BK=32, 4 waves (wave w owns 64x32 cols).
// 1-D grid, XCD-swizzled; nbx = number of M blocks.
// LDS tiles use the row-pair slot swizzle; staging source addresses are
// pre-permuted so global_load_lds's linear dest lands swizzled.
// ---------------------------------------------------------------------------
template <int MODE>
__global__ __launch_bounds__(256) void mfma_gemm(
    const ushort* __restrict__ Ah, const ushort* __restrict__ Al,
    const ushort* __restrict__ Bh, const ushort* __restrict__ Bl,
    float* __restrict__ C0, float* __restrict__ C1, float* __restrict__ C2,
    int ldc, int nbx)
{
    __shared__ ushort sAh[64 * 32], sAl[64 * 32];
    __shared__ ushort sBh[128 * 32], sBl[128 * 32];

    const int t = threadIdx.x;
    // XCD-aware bijective swizzle (gridDim.x % 8 == 0 guaranteed by launcher)
    const int per = (int)gridDim.x >> 3;
    const int id = (blockIdx.x & 7) * per + (blockIdx.x >> 3);
    const int m0 = (id % nbx) * 64;
    const int n0 = (id / nbx) * 128;

    // staging decode: LDS linear chunk p -> (row, kgroup) under the swizzle
    const int lineA = t >> 3;
    const int uA = (t & 7) ^ (lineA & 7);
    const int rowA = lineA * 2 + (uA & 1);
    const int kA = (uA >> 1) * 8;
    const ushort* aH = Ah + (size_t)(m0 + rowA) * HIDDEN + kA;
    const ushort* aL = Al + (size_t)(m0 + rowA) * HIDDEN + kA;
    const ushort* bH0 = Bh + (size_t)(n0 + rowA) * HIDDEN + kA;        // rows 0..63
    const ushort* bH1 = Bh + (size_t)(n0 + 64 + rowA) * HIDDEN + kA;   // rows 64..127
    const ushort* bL0 = Bl + (size_t)(n0 + rowA) * HIDDEN + kA;
    const ushort* bL1 = Bl + (size_t)(n0 + 64 + rowA) * HIDDEN + kA;

    const int lane = t & 63, w = t >> 6;
    const int fr = lane & 15;
    const int fk = lane >> 4;

    // fragment LDS indices, loop-invariant
    int idxA[4], idxB[2];
#pragma unroll
    for (int fi = 0; fi < 4; fi++) idxA[fi] = swz_idx(fi * 16 + fr, fk);
#pragma unroll
    for (int fj = 0; fj < 2; fj++) idxB[fj] = swz_idx(w * 32 + fj * 16 + fr, fk);

    f32x4 acc[4][2];
#pragma unroll
    for (int i = 0; i < 4; i++)
#pragma unroll
        for (int j = 0; j < 2; j++) acc[i][j] = {0.f, 0.f, 0.f, 0.f};

    for (int k0 = 0; k0 < HIDDEN; k0 += 32) {
        __syncthreads();
        gload16(aH + k0, sAh + t * 8);
        gload16(aL + k0, sAl + t * 8);
        gload16(bH0 + k0, sBh + t * 8);
        gload16(bH1 + k0, sBh + 2048 + t * 8);
        gload16(bL0 + k0, sBl + t * 8);
        gload16(bL1 + k0, sBl + 2048 + t * 8);
        __syncthreads();

        bf16x8 ah[4], al[4], bh[2], bl[2];
#pragma unroll
        for (int fi = 0; fi < 4; fi++) {
            ah[fi] = *(const bf16x8*)&sAh[idxA[fi]];
            al[fi] = *(const bf16x8*)&sAl[idxA[fi]];
        }
#pragma unroll
        for (int fj = 0; fj < 2; fj++) {
            bh[fj] = *(const bf16x8*)&sBh[idxB[fj]];
            bl[fj] = *(const bf16x8*)&sBl[idxB[fj]];
        }
#pragma unroll
        for (int fi = 0; fi < 4; fi++)
#pragma unroll
            for (int fj = 0; fj < 2; fj++) {
                acc[fi][fj] = __builtin_amdgcn_mfma_f32_16x16x32_bf16(
                    ah[fi], bh[fj], acc[fi][fj], 0, 0, 0);
                acc[fi][fj] = __builtin_amdgcn_mfma_f32_16x16x32_bf16(
                    ah[fi], bl[fj], acc[fi][fj], 0, 0, 0);
                acc[fi][fj] = __builtin_amdgcn_mfma_f32_16x16x32_bf16(
                    al[fi], bh[fj], acc[fi][fj], 0, 0, 0);
            }
    }

#pragma unroll
    for (int fi = 0; fi < 4; fi++)
#pragma unroll
        for (int fj = 0; fj < 2; fj++) {
            int row0 = m0 + fi * 16 + fk * 4;
            int gcol = n0 + w * 32 + fj * 16 + fr;
            if (MODE == 0) {
                int slot = gcol >> 6, cin = gcol & 63;
                float* dst;
                if (slot < NH) dst = C0 + (size_t)slot * S_LEN * HD;
                else if (slot < NH + NKV) dst = C1 + (size_t)(slot - NH) * S_LEN * HD;
                else dst = C2 + (size_t)(slot - NH - NKV) * S_LEN * HD;
#pragma unroll
                for (int i = 0; i < 4; i++)
                    dst[(size_t)(row0 + i) * HD + cin] = acc[fi][fj][i];
            } else {
#pragma unroll
                for (int i = 0; i < 4; i++)
                    C0[(size_t)(row0 + i) * ldc + gcol] = acc[fi][fj][i];
            }
        }
}

// ---------------------------------------------------------------------------
// RoPE: q in-place fp32; k -> rope'd, split hi/lo, XOR-swizzled bf16 planes.
// khi/klo layout [NKV][S][64], element (s,d) stored at col d ^ ((s&7)<<3).
// ---------------------------------------------------------------------------
__global__ __launch_bounds__(256) void rope_split(
    float* __restrict__ qd, const float* __restrict__ kd,
    const float* __restrict__ cosT, const float* __restrict__ sinT,
    ushort* __restrict__ khi, ushort* __restrict__ klo)
{
    int idx = blockIdx.x * 256 + threadIdx.x;  // (NH+NKV)*S*32 exact
    int d = idx & 31;
    int s = (idx >> 5) & (S_LEN - 1);
    int slot = idx >> 16;
    float c = cosT[s * HD + d];
    float sn = sinT[s * HD + d];
    if (slot < NH) {
        float* base = qd + ((size_t)slot * S_LEN + s) * HD;
        float x1 = base[d], x2 = base[d + 32];
        base[d] = x1 * c - x2 * sn;
        base[d + 32] = x2 * c + x1 * sn;
    } else {
        const float* base = kd + ((size_t)(slot - NH) * S_LEN + s) * HD;
        float x1 = base[d], x2 = base[d + 32];
        float y1 = x1 * c - x2 * sn;
        float y2 = x2 * c + x1 * sn;
        int sw = (s & 7) << 3;
        size_t rb = ((size_t)(slot - NH) * S_LEN + s) * 64;
        ushort h1, l1, h2, l2;
        bsplit(y1, h1, l1);
        bsplit(y2, h2, l2);
        khi[rb + (d ^ sw)] = h1;        klo[rb + (d ^ sw)] = l1;
        khi[rb + ((d + 32) ^ sw)] = h2; klo[rb + ((d + 32) ^ sw)] = l2;
    }
}

// ---------------------------------------------------------------------------
// V -> V^T split planes, swizzled. vthi/vtlo [NKV][64 d][S keys],
// element (d,key) stored at key-low-6 position (key&63) ^ ((d&7)<<3).
// ---------------------------------------------------------------------------
__global__ __launch_bounds__(256) void split_vt(
    const float* __restrict__ v, ushort* __restrict__ vthi,
    ushort* __restrict__ vtlo)
{
    __shared__ float tile[64][65];
    const int b = blockIdx.x;          // NKV * S/64
    const int hk = b >> 5, kt = b & 31;
    const float* src = v + ((size_t)hk * S_LEN + kt * 64) * 64;
    const int t = threadIdx.x;
    {
        int row = t >> 2, dg = (t & 3) * 16;
#pragma unroll
        for (int i = 0; i < 4; i++) {
            float4 x = *(const float4*)(src + row * 64 + dg + i * 4);
            tile[row][dg + i * 4 + 0] = x.x;
            tile[row][dg + i * 4 + 1] = x.y;
            tile[row][dg + i * 4 + 2] = x.z;
            tile[row][dg + i * 4 + 3] = x.w;
        }
    }
    __syncthreads();
    const int d = t >> 2, kg = (t & 3) * 16;
    ushort hi16[16], lo16[16];
#pragma unroll
    for (int i = 0; i < 16; i++) bsplit(tile[kg + i][d], hi16[i], lo16[i]);
    const int sw = (d & 7) << 3;
    size_t rowb = ((size_t)hk * 64 + d) * S_LEN + kt * 64;
    int base = kg ^ (sw & 48);
    int o0 = base + (sw & 8);
    int o1 = base + (8 ^ (sw & 8));
    *(ushort4*)&vthi[rowb + o0]     = *(ushort4*)&hi16[0];
    *(ushort4*)&vthi[rowb + o0 + 4] = *(ushort4*)&hi16[4];
    *(ushort4*)&vthi[rowb + o1]     = *(ushort4*)&hi16[8];
    *(ushort4*)&vthi[rowb + o1 + 4] = *(ushort4*)&hi16[12];
    *(ushort4*)&vtlo[rowb + o0]     = *(ushort4*)&lo16[0];
    *(ushort4*)&vtlo[rowb + o0 + 4] = *(ushort4*)&lo16[4];
    *(ushort4*)&vtlo[rowb + o1]     = *(ushort4*)&lo16[8];
    *(ushort4*)&vtlo[rowb + o1 + 4] = *(ushort4*)&lo16[12];
}

// ---------------------------------------------------------------------------
// MFMA flash attention; epilogue writes split hi/lo planes of O directly.
// ---------------------------------------------------------------------------
__global__ __launch_bounds__(256) void attn_mfma(
    const float* __restrict__ q,
    const ushort* __restrict__ khi, const ushort* __restrict__ klo,
    const ushort* __restrict__ vthi, const ushort* __restrict__ vtlo,
    ushort* __restrict__ oH, ushort* __restrict__ oL)
{
    __shared__ ushort uni[16384];
    __shared__ ushort Pl[4][32 * 72];
    __shared__ float corrw[4][32];
    __shared__ float lw[4][32];

    const int t = threadIdx.x;
    const int lane = t & 63, w = t >> 6;
    const int hd_ = blockIdx.y, hk = hd_ >> 2;
    const int qt = (int)gridDim.x - 1 - (int)blockIdx.x;
    const int q0 = qt * 128;
    const int l31 = lane & 31;
    const int dh = (lane >> 5) * 8;

    {
        const int row = t >> 1, dg = (t & 1) * 32;
        const float* src = q + ((size_t)hd_ * S_LEN + q0 + row) * HD + dg;
        const int sw = (row & 7) << 3;
#pragma unroll
        for (int i = 0; i < 8; i++) {
            float4 v4 = *(const float4*)(src + i * 4);
            float xs[4] = {v4.x, v4.y, v4.z, v4.w};
            ushort h4[4], l4[4];
#pragma unroll
            for (int j = 0; j < 4; j++) bsplit(xs[j], h4[j], l4[j]);
            int idx = (row * 64 + dg + i * 4) ^ sw;
            *(ushort4*)&uni[idx] = *(ushort4*)&h4[0];
            *(ushort4*)&uni[8192 + idx] = *(ushort4*)&l4[0];
        }
    }
    __syncthreads();
    bf16x8 qh[4], ql[4];
    {
        const int qrow = w * 32 + l31;
        const int sw = (qrow & 7) << 3;
#pragma unroll
        for (int ks = 0; ks < 4; ks++) {
            int idx = (qrow * 64 + ks * 16 + dh) ^ sw;
            qh[ks] = *(const bf16x8*)&uni[idx];
            ql[ks] = *(const bf16x8*)&uni[8192 + idx];
        }
    }

    f32x16 accO0, accO1;
#pragma unroll
    for (int r = 0; r < 16; r++) { accO0[r] = 0.f; accO1[r] = 0.f; }
    float m_run = -1e30f, l_run = 0.f;

    const ushort* khi_t = khi + (size_t)hk * S_LEN * 64;
    const ushort* klo_t = klo + (size_t)hk * S_LEN * 64;
    const ushort* vth_t = vthi + (size_t)hk * 64 * S_LEN;
    const ushort* vtl_t = vtlo + (size_t)hk * 64 * S_LEN;
    ushort* Pw = &Pl[w][0];
    const int swk = (l31 & 7) << 3;
    const int qg = q0 + w * 32 + l31;
    const int d0s = t >> 3, kks = (t & 7) * 8;

    const int ntiles = 2 * qt + 2;
    for (int tile = 0; tile < ntiles; tile++) {
        const int k0 = tile * 64;
        __syncthreads();
        {
            const ushort* a = khi_t + k0 * 64;
            const ushort* b = klo_t + k0 * 64;
            gload16(a + t * 8, &uni[t * 8]);
            gload16(a + 2048 + t * 8, &uni[2048 + t * 8]);
            gload16(b + t * 8, &uni[4096 + t * 8]);
            gload16(b + 2048 + t * 8, &uni[6144 + t * 8]);
            gload16(vth_t + (size_t)d0s * S_LEN + k0 + kks, &uni[8192 + t * 8]);
            gload16(vth_t + (size_t)(d0s + 32) * S_LEN + k0 + kks, &uni[10240 + t * 8]);
            gload16(vtl_t + (size_t)d0s * S_LEN + k0 + kks, &uni[12288 + t * 8]);
            gload16(vtl_t + (size_t)(d0s + 32) * S_LEN + k0 + kks, &uni[14336 + t * 8]);
        }
        __syncthreads();

        f32x16 sc0, sc1;
#pragma unroll
        for (int r = 0; r < 16; r++) { sc0[r] = 0.f; sc1[r] = 0.f; }
#pragma unroll
        for (int ks = 0; ks < 4; ks++) {
            int off = ks * 16 + dh;
            int i0 = (l31 * 64 + off) ^ swk;
            int i1 = ((l31 + 32) * 64 + off) ^ swk;
            bf16x8 kh0 = *(const bf16x8*)&uni[i0];
            bf16x8 kl0 = *(const bf16x8*)&uni[4096 + i0];
            bf16x8 kh1 = *(const bf16x8*)&uni[i1];
            bf16x8 kl1 = *(const bf16x8*)&uni[4096 + i1];
            sc0 = __builtin_amdgcn_mfma_f32_32x32x16_bf16(kh0, qh[ks], sc0, 0, 0, 0);
            sc1 = __builtin_amdgcn_mfma_f32_32x32x16_bf16(kh1, qh[ks], sc1, 0, 0, 0);
            sc0 = __builtin_amdgcn_mfma_f32_32x32x16_bf16(kh0, ql[ks], sc0, 0, 0, 0);
            sc1 = __builtin_amdgcn_mfma_f32_32x32x16_bf16(kh1, ql[ks], sc1, 0, 0, 0);
            sc0 = __builtin_amdgcn_mfma_f32_32x32x16_bf16(kl0, qh[ks], sc0, 0, 0, 0);
            sc1 = __builtin_amdgcn_mfma_f32_32x32x16_bf16(kl1, qh[ks], sc1, 0, 0, 0);
        }

        const bool maskt = (tile >= 2 * qt);
        float mx = -1e30f;
#pragma unroll
        for (int r = 0; r < 16; r++) {
            int krow = (r & 3) + 8 * (r >> 2) + 4 * (lane >> 5);
            float v0 = sc0[r] * SCALE;
            float v1 = sc1[r] * SCALE;
            if (maskt) {
                if (k0 + krow > qg) v0 = -1e30f;
                if (k0 + 32 + krow > qg) v1 = -1e30f;
            }
            sc0[r] = v0; sc1[r] = v1;
            mx = fmaxf(mx, fmaxf(v0, v1));
        }
        mx = fmaxf(mx, __shfl_xor(mx, 32));

        float corr = 1.f;
        const bool skip = __all(mx - m_run <= 8.0f);
        if (!skip) {
            float m_new = fmaxf(m_run, mx);
            corr = __expf(m_run - m_new);
            m_run = m_new;
            if (lane < 32) corrw[w][l31] = corr;
        }
        float sum = 0.f;
#pragma unroll
        for (int r = 0; r < 16; r++) {
            float p0 = __expf(sc0[r] - m_run);
            float p1 = __expf(sc1[r] - m_run);
            sc0[r] = p0; sc1[r] = p1;
            sum += p0 + p1;
        }
        sum += __shfl_xor(sum, 32);
        l_run = l_run * corr + sum;

#pragma unroll
        for (int r = 0; r < 16; r += 2) {
            int krow = (r & 3) + 8 * (r >> 2) + 4 * (lane >> 5);
            uint32_t b0 = (uint32_t)bf16r(sc0[r]) | ((uint32_t)bf16r(sc0[r + 1]) << 16);
            uint32_t b1 = (uint32_t)bf16r(sc1[r]) | ((uint32_t)bf16r(sc1[r + 1]) << 16);
            *(uint32_t*)&Pw[l31 * 72 + krow] = b0;
            *(uint32_t*)&Pw[l31 * 72 + 32 + krow] = b1;
        }

        if (!skip) {
#pragma unroll
            for (int r = 0; r < 16; r++) {
                int qrow = (r & 3) + 8 * (r >> 2) + 4 * (lane >> 5);
                float cr = corrw[w][qrow];
                accO0[r] *= cr; accO1[r] *= cr;
            }
        }

#pragma unroll
        for (int ks = 0; ks < 4; ks++) {
            bf16x8 pa = *(const bf16x8*)&Pw[l31 * 72 + ks * 16 + dh];
            int ia = (l31 * 64 + ks * 16 + dh) ^ swk;
            int ib = ((l31 + 32) * 64 + ks * 16 + dh) ^ swk;
            bf16x8 vh0 = *(const bf16x8*)&uni[8192 + ia];
            bf16x8 vh1 = *(const bf16x8*)&uni[8192 + ib];
            bf16x8 vl0 = *(const bf16x8*)&uni[12288 + ia];
            bf16x8 vl1 = *(const bf16x8*)&uni[12288 + ib];
            accO0 = __builtin_amdgcn_mfma_f32_32x32x16_bf16(pa, vh0, accO0, 0, 0, 0);
            accO1 = __builtin_amdgcn_mfma_f32_32x32x16_bf16(pa, vh1, accO1, 0, 0, 0);
            accO0 = __builtin_amdgcn_mfma_f32_32x32x16_bf16(pa, vl0, accO0, 0, 0, 0);
            accO1 = __builtin_amdgcn_mfma_f32_32x32x16_bf16(pa, vl1, accO1, 0, 0, 0);
        }
    }

    // epilogue: O/l -> split bf16 planes directly
    if (lane < 32) lw[w][l31] = l_run;
#pragma unroll
    for (int r = 0; r < 16; r++) {
        int qrow = (r & 3) + 8 * (r >> 2) + 4 * (lane >> 5);
        float inv = 1.0f / lw[w][qrow];
        float v0 = accO0[r] * inv;
        float v1 = accO1[r] * inv;
        size_t base = (size_t)(q0 + w * 32 + qrow) * (NH * HD) + hd_ * 64 + l31;
        ushort hh, ll;
        bsplit(v0, hh, ll);
        oH[base] = hh; oL[base] = ll;
        bsplit(v1, hh, ll);
        oH[base + 32] = hh; oL[base + 32] = ll;
    }
}

// ---------------------------------------------------------------------------
extern "C" void kernel_launch(void* const* d_in, const int* in_sizes, int n_in,
                              void* d_out, int out_size, void* d_ws, size_t ws_size,
                              hipStream_t stream) {
    const float* hidden = (const float*)d_in[0];
    const float* cosT   = (const float*)d_in[1];
    const float* sinT   = (const float*)d_in[2];
    // d_in[3] = attention_mask: exactly causal -> analytic
    const float* wq = (const float*)d_in[4];
    const float* wk = (const float*)d_in[5];
    const float* wv = (const float*)d_in[6];
    const float* wo = (const float*)d_in[7];
    float* out = (float*)d_out;

    char* wsb = (char*)d_ws;
    auto alloc = [&](size_t bytes) { char* p = wsb; wsb += (bytes + 255) & ~255ULL; return p; };
    float* q = (float*)alloc((size_t)NH * S_LEN * HD * 4);
    float* k = (float*)alloc((size_t)NKV * S_LEN * HD * 4);
    float* v = (float*)alloc((size_t)NKV * S_LEN * HD * 4);
    ushort* hidH = (ushort*)alloc((size_t)S_LEN * HIDDEN * 2);
    ushort* hidL = (ushort*)alloc((size_t)S_LEN * HIDDEN * 2);
    ushort* WcH  = (ushort*)alloc((size_t)3072 * HIDDEN * 2);
    ushort* WcL  = (ushort*)alloc((size_t)3072 * HIDDEN * 2);
    ushort* woH  = (ushort*)alloc((size_t)HIDDEN * 2048 * 2);
    ushort* woL  = (ushort*)alloc((size_t)HIDDEN * 2048 * 2);
    ushort* oH   = (ushort*)alloc((size_t)S_LEN * 2048 * 2);
    ushort* oL   = (ushort*)alloc((size_t)S_LEN * 2048 * 2);
    // K/V planes alias hidH (dead after the QKV GEMM): 4 x 1,048,576 ushorts.
    ushort* khi  = hidH;
    ushort* klo  = hidH + 1048576;
    ushort* vthi = hidH + 2097152;
    ushort* vtlo = hidH + 3145728;

    dim3 blk(256);
    {
        int n4 = S_LEN * HIDDEN / 4;
        split_bf16<<<(n4 + 255) / 256, blk, 0, stream>>>(hidden, hidH, hidL, n4);
        int nq4 = NH * HD * HIDDEN / 4;
        split_bf16<<<(nq4 + 255) / 256, blk, 0, stream>>>(wq, WcH, WcL, nq4);
        int nk4 = NKV * HD * HIDDEN / 4;
        size_t off = (size_t)NH * HD * HIDDEN;
        split_bf16<<<(nk4 + 255) / 256, blk, 0, stream>>>(wk, WcH + off, WcL + off, nk4);
        size_t off2 = off + (size_t)NKV * HD * HIDDEN;
        split_bf16<<<(nk4 + 255) / 256, blk, 0, stream>>>(wv, WcH + off2, WcL + off2, nk4);
        int nw4 = HIDDEN * 2048 / 4;
        split_bf16<<<(nw4 + 255) / 256, blk, 0, stream>>>(wo, woH, woL, nw4);
    }
    // QKV projection: M=2048 (32 blocks), N=3072 (24 blocks) -> 768 (%8==0)
    mfma_gemm<0><<<dim3(32 * 24), blk, 0, stream>>>(
        hidH, hidL, WcH, WcL, q, k, v, 0, 32);
    // RoPE (q in place) + K split planes (overwrites hidH region — now dead)
    rope_split<<<(NH + NKV) * S_LEN * 32 / 256, blk, 0, stream>>>(
        q, k, cosT, sinT, khi, klo);
    // V^T split planes
    split_vt<<<NKV * (S_LEN / 64), blk, 0, stream>>>(v, vthi, vtlo);
    // flash attention -> split O planes
    attn_mfma<<<dim3(S_LEN / 128, NH), blk, 0, stream>>>(
        q, khi, klo, vthi, vtlo, oH, oL);
    // out projection: M=2048 (32), N=2048 (16) -> 512 blocks (%8==0)
    mfma_gemm<1><<<dim3(32 * 16), blk, 0, stream>>>(
        oH, oL, woH, woL, out, nullptr, nullptr, 2048, 32);
}

// Round 9
// 385.937 us; speedup vs baseline: 3.5296x; 1.0501x over previous
//
#include <hip/hip_runtime.h>
#include <hip/hip_bf16.h>
#include <stdint.h>

// Fused GQA attention layer.
// Round 5e (resubmit; R5-R8 benches failed at GPU acquisition): attention
// rework — double-buffered K/V staging with counted vmcnt (never 0 in-loop) +
// raw barriers, in-register P via v_permlane32_swap_b32 (inline asm), split
// MFMA chains, exp2-domain softmax (scale folded into Q), complement-paired
// grid.

#define S_LEN 2048
#define HIDDEN 2048
#define NH 32
#define NKV 8
#define HD 64
// SCALE * log2(e): scores computed directly in exp2 domain
#define SCALE_L2E 0.18033688011112042f

typedef __bf16 bf16x8 __attribute__((ext_vector_type(8)));
typedef float f32x4 __attribute__((ext_vector_type(4)));
typedef float f32x16 __attribute__((ext_vector_type(16)));

__device__ inline void gload16(const void* g, void* l) {
    using GP = const __attribute__((address_space(1))) uint32_t*;
    using LP = __attribute__((address_space(3))) uint32_t*;
    __builtin_amdgcn_global_load_lds((GP)g, (LP)(uint32_t)(uintptr_t)l, 16, 0, 0);
}

__device__ inline ushort bf16r(float x) {
    uint32_t u = __float_as_uint(x);
    return (ushort)((u + 0x7FFFu + ((u >> 16) & 1u)) >> 16);
}
__device__ inline void bsplit(float x, ushort& h, ushort& l) {
    uint32_t u = __float_as_uint(x);
    uint32_t hr = (u + 0x7FFFu + ((u >> 16) & 1u)) >> 16;
    float r = x - __uint_as_float(hr << 16);
    uint32_t ul = __float_as_uint(r);
    l = (ushort)((ul + 0x7FFFu + ((ul >> 16) & 1u)) >> 16);
    h = (ushort)hr;
}
__device__ inline uint32_t pk2(float a, float b) {
    return (uint32_t)bf16r(a) | ((uint32_t)bf16r(b) << 16);
}

// ---------------------------------------------------------------------------
// fp32 -> (bf16 hi, bf16 lo) planes, vectorized x4.
// ---------------------------------------------------------------------------
__global__ __launch_bounds__(256) void split_bf16(
    const float* __restrict__ src, ushort* __restrict__ hi,
    ushort* __restrict__ lo, int n4)
{
    int i = blockIdx.x * 256 + threadIdx.x;
    if (i >= n4) return;
    float4 v = ((const float4*)src)[i];
    float x[4] = {v.x, v.y, v.z, v.w};
    ushort h[4], l[4];
#pragma unroll
    for (int j = 0; j < 4; j++) bsplit(x[j], h[j], l[j]);
    ushort4 ho = {h[0], h[1], h[2], h[3]};
    ushort4 lv = {l[0], l[1], l[2], l[3]};
    ((ushort4*)hi)[i] = ho;
    ((ushort4*)lo)[i] = lv;
}

// ---------------------------------------------------------------------------
// Split-bf16 MFMA GEMM (unchanged from round 4).
// ---------------------------------------------------------------------------
__device__ inline int swz_idx(int row, int fk) {
    int line = row >> 1;
    int inner = (((fk << 1) | (row & 1)) ^ (line & 7));
    return line * 64 + inner * 8;
}

template <int MODE>
__global__ __launch_bounds__(256) void mfma_gemm(
    const ushort* __restrict__ Ah, const ushort* __restrict__ Al,
    const ushort* __restrict__ Bh, const ushort* __restrict__ Bl,
    float* __restrict__ C0, float* __restrict__ C1, float* __restrict__ C2,
    int ldc, int nbx)
{
    __shared__ ushort sAh[64 * 32], sAl[64 * 32];
    __shared__ ushort sBh[128 * 32], sBl[128 * 32];

    const int t = threadIdx.x;
    const int per = (int)gridDim.x >> 3;
    const int id = (blockIdx.x & 7) * per + (blockIdx.x >> 3);
    const int m0 = (id % nbx) * 64;
    const int n0 = (id / nbx) * 128;

    const int lineA = t >> 3;
    const int uA = (t & 7) ^ (lineA & 7);
    const int rowA = lineA * 2 + (uA & 1);
    const int kA = (uA >> 1) * 8;
    const ushort* aH = Ah + (size_t)(m0 + rowA) * HIDDEN + kA;
    const ushort* aL = Al + (size_t)(m0 + rowA) * HIDDEN + kA;
    const ushort* bH0 = Bh + (size_t)(n0 + rowA) * HIDDEN + kA;
    const ushort* bH1 = Bh + (size_t)(n0 + 64 + rowA) * HIDDEN + kA;
    const ushort* bL0 = Bl + (size_t)(n0 + rowA) * HIDDEN + kA;
    const ushort* bL1 = Bl + (size_t)(n0 + 64 + rowA) * HIDDEN + kA;

    const int lane = t & 63, w = t >> 6;
    const int fr = lane & 15;
    const int fk = lane >> 4;

    int idxA[4], idxB[2];
#pragma unroll
    for (int fi = 0; fi < 4; fi++) idxA[fi] = swz_idx(fi * 16 + fr, fk);
#pragma unroll
    for (int fj = 0; fj < 2; fj++) idxB[fj] = swz_idx(w * 32 + fj * 16 + fr, fk);

    f32x4 acc[4][2];
#pragma unroll
    for (int i = 0; i < 4; i++)
#pragma unroll
        for (int j = 0; j < 2; j++) acc[i][j] = {0.f, 0.f, 0.f, 0.f};

    for (int k0 = 0; k0 < HIDDEN; k0 += 32) {
        __syncthreads();
        gload16(aH + k0, sAh + t * 8);
        gload16(aL + k0, sAl + t * 8);
        gload16(bH0 + k0, sBh + t * 8);
        gload16(bH1 + k0, sBh + 2048 + t * 8);
        gload16(bL0 + k0, sBl + t * 8);
        gload16(bL1 + k0, sBl + 2048 + t * 8);
        __syncthreads();

        bf16x8 ah[4], al[4], bh[2], bl[2];
#pragma unroll
        for (int fi = 0; fi < 4; fi++) {
            ah[fi] = *(const bf16x8*)&sAh[idxA[fi]];
            al[fi] = *(const bf16x8*)&sAl[idxA[fi]];
        }
#pragma unroll
        for (int fj = 0; fj < 2; fj++) {
            bh[fj] = *(const bf16x8*)&sBh[idxB[fj]];
            bl[fj] = *(const bf16x8*)&sBl[idxB[fj]];
        }
#pragma unroll
        for (int fi = 0; fi < 4; fi++)
#pragma unroll
            for (int fj = 0; fj < 2; fj++) {
                acc[fi][fj] = __builtin_amdgcn_mfma_f32_16x16x32_bf16(
                    ah[fi], bh[fj], acc[fi][fj], 0, 0, 0);
                acc[fi][fj] = __builtin_amdgcn_mfma_f32_16x16x32_bf16(
                    ah[fi], bl[fj], acc[fi][fj], 0, 0, 0);
                acc[fi][fj] = __builtin_amdgcn_mfma_f32_16x16x32_bf16(
                    al[fi], bh[fj], acc[fi][fj], 0, 0, 0);
            }
    }

#pragma unroll
    for (int fi = 0; fi < 4; fi++)
#pragma unroll
        for (int fj = 0; fj < 2; fj++) {
            int row0 = m0 + fi * 16 + fk * 4;
            int gcol = n0 + w * 32 + fj * 16 + fr;
            if (MODE == 0) {
                int slot = gcol >> 6, cin = gcol & 63;
                float* dst;
                if (slot < NH) dst = C0 + (size_t)slot * S_LEN * HD;
                else if (slot < NH + NKV) dst = C1 + (size_t)(slot - NH) * S_LEN * HD;
                else dst = C2 + (size_t)(slot - NH - NKV) * S_LEN * HD;
#pragma unroll
                for (int i = 0; i < 4; i++)
                    dst[(size_t)(row0 + i) * HD + cin] = acc[fi][fj][i];
            } else {
#pragma unroll
                for (int i = 0; i < 4; i++)
                    C0[(size_t)(row0 + i) * ldc + gcol] = acc[fi][fj][i];
            }
        }
}

// ---------------------------------------------------------------------------
// RoPE: q in-place fp32; k -> rope'd, split hi/lo, XOR-swizzled bf16 planes.
// ---------------------------------------------------------------------------
__global__ __launch_bounds__(256) void rope_split(
    float* __restrict__ qd, const float* __restrict__ kd,
    const float* __restrict__ cosT, const float* __restrict__ sinT,
    ushort* __restrict__ khi, ushort* __restrict__ klo)
{
    int idx = blockIdx.x * 256 + threadIdx.x;
    int d = idx & 31;
    int s = (idx >> 5) & (S_LEN - 1);
    int slot = idx >> 16;
    float c = cosT[s * HD + d];
    float sn = sinT[s * HD + d];
    if (slot < NH) {
        float* base = qd + ((size_t)slot * S_LEN + s) * HD;
        float x1 = base[d], x2 = base[d + 32];
        base[d] = x1 * c - x2 * sn;
        base[d + 32] = x2 * c + x1 * sn;
    } else {
        const float* base = kd + ((size_t)(slot - NH) * S_LEN + s) * HD;
        float x1 = base[d], x2 = base[d + 32];
        float y1 = x1 * c - x2 * sn;
        float y2 = x2 * c + x1 * sn;
        int sw = (s & 7) << 3;
        size_t rb = ((size_t)(slot - NH) * S_LEN + s) * 64;
        ushort h1, l1, h2, l2;
        bsplit(y1, h1, l1);
        bsplit(y2, h2, l2);
        khi[rb + (d ^ sw)] = h1;        klo[rb + (d ^ sw)] = l1;
        khi[rb + ((d + 32) ^ sw)] = h2; klo[rb + ((d + 32) ^ sw)] = l2;
    }
}

// ---------------------------------------------------------------------------
// V -> V^T split planes, swizzled (unchanged).
// ---------------------------------------------------------------------------
__global__ __launch_bounds__(256) void split_vt(
    const float* __restrict__ v, ushort* __restrict__ vthi,
    ushort* __restrict__ vtlo)
{
    __shared__ float tile[64][65];
    const int b = blockIdx.x;
    const int hk = b >> 5, kt = b & 31;
    const float* src = v + ((size_t)hk * S_LEN + kt * 64) * 64;
    const int t = threadIdx.x;
    {
        int row = t >> 2, dg = (t & 3) * 16;
#pragma unroll
        for (int i = 0; i < 4; i++) {
            float4 x = *(const float4*)(src + row * 64 + dg + i * 4);
            tile[row][dg + i * 4 + 0] = x.x;
            tile[row][dg + i * 4 + 1] = x.y;
            tile[row][dg + i * 4 + 2] = x.z;
            tile[row][dg + i * 4 + 3] = x.w;
        }
    }
    __syncthreads();
    const int d = t >> 2, kg = (t & 3) * 16;
    ushort hi16[16], lo16[16];
#pragma unroll
    for (int i = 0; i < 16; i++) bsplit(tile[kg + i][d], hi16[i], lo16[i]);
    const int sw = (d & 7) << 3;
    size_t rowb = ((size_t)hk * 64 + d) * S_LEN + kt * 64;
    int base = kg ^ (sw & 48);
    int o0 = base + (sw & 8);
    int o1 = base + (8 ^ (sw & 8));
    *(ushort4*)&vthi[rowb + o0]     = *(ushort4*)&hi16[0];
    *(ushort4*)&vthi[rowb + o0 + 4] = *(ushort4*)&hi16[4];
    *(ushort4*)&vthi[rowb + o1]     = *(ushort4*)&hi16[8];
    *(ushort4*)&vthi[rowb + o1 + 4] = *(ushort4*)&hi16[12];
    *(ushort4*)&vtlo[rowb + o0]     = *(ushort4*)&lo16[0];
    *(ushort4*)&vtlo[rowb + o0 + 4] = *(ushort4*)&lo16[4];
    *(ushort4*)&vtlo[rowb + o1]     = *(ushort4*)&lo16[8];
    *(ushort4*)&vtlo[rowb + o1 + 4] = *(ushort4*)&lo16[12];
}

// ---------------------------------------------------------------------------
// MFMA flash attention, round 5.
// Grid: 512 blocks 1-D, 4 waves. QBLK=128 (wave owns 32 q), KVBLK=64.
// Double-buffered LDS staging (counted vmcnt, raw barriers); in-register P.
// ---------------------------------------------------------------------------
__global__ __launch_bounds__(256, 2) void attn_mfma(
    const float* __restrict__ q,
    const ushort* __restrict__ khi, const ushort* __restrict__ klo,
    const ushort* __restrict__ vthi, const ushort* __restrict__ vtlo,
    ushort* __restrict__ oH, ushort* __restrict__ oL)
{
    __shared__ ushort uni[2][16384];   // 2 x 32KB: Khi|Klo|Vth|Vtl (8KB each)
    __shared__ float corrw[4][32];
    __shared__ float lw[4][32];

    const int t = threadIdx.x;
    const int lane = t & 63, w = t >> 6;
    const int hi = lane >> 5;
    const int l31 = lane & 31;
    const int dh = hi * 8;

    // complement-paired mapping: ids b and b+256 sum to 36 tiles
    const int id = blockIdx.x;
    const int hd_ = id & 31;
    const int g = id >> 5;
    const int qt = (g < 8) ? (15 - g) : (g - 8);
    const int q0 = qt * 128;
    const int hk = hd_ >> 2;

    const ushort* khi_t = khi + (size_t)hk * S_LEN * 64;
    const ushort* klo_t = klo + (size_t)hk * S_LEN * 64;
    const ushort* vth_t = vthi + (size_t)hk * 64 * S_LEN;
    const ushort* vtl_t = vtlo + (size_t)hk * 64 * S_LEN;
    const int d0s = t >> 3, kks = (t & 7) * 8;
    const int swk = (l31 & 7) << 3;
    const int qg = q0 + w * 32 + l31;
    const int ntiles = 2 * qt + 2;

    auto MF = [](bf16x8 a, bf16x8 b, f32x16 c) {
        return __builtin_amdgcn_mfma_f32_32x32x16_bf16(a, b, c, 0, 0, 0);
    };
    auto STAGE = [&](int k0, ushort* buf) {
        const ushort* a = khi_t + (size_t)k0 * 64;
        const ushort* b = klo_t + (size_t)k0 * 64;
        gload16(a + t * 8, buf + t * 8);
        gload16(a + 2048 + t * 8, buf + 2048 + t * 8);
        gload16(b + t * 8, buf + 4096 + t * 8);
        gload16(b + 2048 + t * 8, buf + 6144 + t * 8);
        gload16(vth_t + (size_t)d0s * S_LEN + k0 + kks, buf + 8192 + t * 8);
        gload16(vth_t + (size_t)(d0s + 32) * S_LEN + k0 + kks, buf + 10240 + t * 8);
        gload16(vtl_t + (size_t)d0s * S_LEN + k0 + kks, buf + 12288 + t * 8);
        gload16(vtl_t + (size_t)(d0s + 32) * S_LEN + k0 + kks, buf + 14336 + t * 8);
    };

    // prologue: start tile-0 loads into buf0 while Q stages through buf1
    STAGE(0, uni[0]);
    {
        const int row = t >> 1, dg = (t & 1) * 32;
        const float* src = q + ((size_t)hd_ * S_LEN + q0 + row) * HD + dg;
        const int sw = (row & 7) << 3;
#pragma unroll
        for (int i = 0; i < 8; i++) {
            float4 v4 = *(const float4*)(src + i * 4);
            float xs[4] = {v4.x, v4.y, v4.z, v4.w};
            ushort h4[4], l4[4];
#pragma unroll
            for (int j = 0; j < 4; j++) bsplit(xs[j] * SCALE_L2E, h4[j], l4[j]);
            int idx = (row * 64 + dg + i * 4) ^ sw;
            *(ushort4*)&uni[1][idx] = *(ushort4*)&h4[0];
            *(ushort4*)&uni[1][8192 + idx] = *(ushort4*)&l4[0];
        }
    }
    __syncthreads();
    bf16x8 qh[4], ql[4];
    {
        const int qrow = w * 32 + l31;
        const int sw = (qrow & 7) << 3;
#pragma unroll
        for (int ks = 0; ks < 4; ks++) {
            int idx = (qrow * 64 + ks * 16 + dh) ^ sw;
            qh[ks] = *(const bf16x8*)&uni[1][idx];
            ql[ks] = *(const bf16x8*)&uni[1][8192 + idx];
        }
    }
    __syncthreads();  // buf1 free for tile-1 staging

    f32x16 accO0, accO1;
#pragma unroll
    for (int r = 0; r < 16; r++) { accO0[r] = 0.f; accO1[r] = 0.f; }
    float m_run = -1e30f, l_run = 0.f;

    for (int tile = 0; tile < ntiles; tile++) {
        const int k0 = tile * 64;
        const ushort* U = uni[tile & 1];
        if (tile + 1 < ntiles) {
            STAGE(k0 + 64, uni[(tile + 1) & 1]);
            asm volatile("s_waitcnt vmcnt(8)" ::: "memory");
        } else {
            asm volatile("s_waitcnt vmcnt(0)" ::: "memory");
        }
        __builtin_amdgcn_s_barrier();

        // ---- QK^T, split chains (6-deep) ----
        f32x16 sa0, sa1, sb0, sb1;
#pragma unroll
        for (int r = 0; r < 16; r++) { sa0[r] = 0.f; sa1[r] = 0.f; sb0[r] = 0.f; sb1[r] = 0.f; }
        __builtin_amdgcn_s_setprio(1);
#pragma unroll
        for (int ks = 0; ks < 2; ks++) {
            int off = ks * 16 + dh;
            int i0 = (l31 * 64 + off) ^ swk;
            int i1 = ((l31 + 32) * 64 + off) ^ swk;
            bf16x8 kh0 = *(const bf16x8*)&U[i0];
            bf16x8 kl0 = *(const bf16x8*)&U[4096 + i0];
            bf16x8 kh1 = *(const bf16x8*)&U[i1];
            bf16x8 kl1 = *(const bf16x8*)&U[4096 + i1];
            sa0 = MF(kh0, qh[ks], sa0); sa1 = MF(kh1, qh[ks], sa1);
            sa0 = MF(kh0, ql[ks], sa0); sa1 = MF(kh1, ql[ks], sa1);
            sa0 = MF(kl0, qh[ks], sa0); sa1 = MF(kl1, qh[ks], sa1);
        }
#pragma unroll
        for (int ks = 2; ks < 4; ks++) {
            int off = ks * 16 + dh;
            int i0 = (l31 * 64 + off) ^ swk;
            int i1 = ((l31 + 32) * 64 + off) ^ swk;
            bf16x8 kh0 = *(const bf16x8*)&U[i0];
            bf16x8 kl0 = *(const bf16x8*)&U[4096 + i0];
            bf16x8 kh1 = *(const bf16x8*)&U[i1];
            bf16x8 kl1 = *(const bf16x8*)&U[4096 + i1];
            sb0 = MF(kh0, qh[ks], sb0); sb1 = MF(kh1, qh[ks], sb1);
            sb0 = MF(kh0, ql[ks], sb0); sb1 = MF(kh1, ql[ks], sb1);
            sb0 = MF(kl0, qh[ks], sb0); sb1 = MF(kl1, qh[ks], sb1);
        }
        __builtin_amdgcn_s_setprio(0);
        f32x16 sc0 = sa0 + sb0;
        f32x16 sc1 = sa1 + sb1;

        // ---- mask + online softmax (exp2 domain, scores pre-scaled) ----
        if (tile >= 2 * qt) {
#pragma unroll
            for (int r = 0; r < 16; r++) {
                int krow = (r & 3) + 8 * (r >> 2) + 4 * hi;
                if (k0 + krow > qg) sc0[r] = -1e30f;
                if (k0 + 32 + krow > qg) sc1[r] = -1e30f;
            }
        }
        float mx = -1e30f;
#pragma unroll
        for (int r = 0; r < 16; r++) mx = fmaxf(mx, fmaxf(sc0[r], sc1[r]));
        mx = fmaxf(mx, __shfl_xor(mx, 32));

        const bool skip = __all(mx - m_run <= 8.0f);
        float corr = 1.f;
        if (!skip) {
            float m_new = fmaxf(m_run, mx);
            corr = exp2f(m_run - m_new);
            m_run = m_new;
            if (lane < 32) corrw[w][l31] = corr;
        }
        float sum = 0.f;
#pragma unroll
        for (int r = 0; r < 16; r++) {
            float p0 = exp2f(sc0[r] - m_run);
            float p1 = exp2f(sc1[r] - m_run);
            sc0[r] = p0; sc1[r] = p1;
            sum += p0 + p1;
        }
        sum += __shfl_xor(sum, 32);
        l_run = l_run * corr + sum;

        // ---- in-register P -> A-fragments via v_permlane32_swap_b32 ----
        // Lane (hi-half) owns keys {0-3,8-11,16-19,24-27}+4*hi of sc0 (keys
        // 0..31) and same +32 of sc1. pa[ks] needs P[q=l31][key=ks*16+hi*8+j].
        // swap(pk(r0,r1), pk(r4,r5)): DST.row1 <-> SRC.row0 gives both halves.
        bf16x8 pa[4];
        {
            uint32_t c0, c1, c2, c3;
            union { uint32_t u[4]; bf16x8 v; } uu;
#define BUILD_PA(SC, RB, DST)                                              \
            c0 = pk2((SC)[RB + 0], (SC)[RB + 1]);                          \
            c1 = pk2((SC)[RB + 2], (SC)[RB + 3]);                          \
            c2 = pk2((SC)[RB + 4], (SC)[RB + 5]);                          \
            c3 = pk2((SC)[RB + 6], (SC)[RB + 7]);                          \
            asm volatile("v_permlane32_swap_b32 %0, %1"                    \
                         : "+v"(c0), "+v"(c2));                            \
            asm volatile("v_permlane32_swap_b32 %0, %1"                    \
                         : "+v"(c1), "+v"(c3));                            \
            uu.u[0] = c0; uu.u[1] = c1; uu.u[2] = c2; uu.u[3] = c3;        \
            DST = uu.v;
            BUILD_PA(sc0, 0, pa[0]);
            BUILD_PA(sc0, 8, pa[1]);
            BUILD_PA(sc1, 0, pa[2]);
            BUILD_PA(sc1, 8, pa[3]);
#undef BUILD_PA
        }

        // ---- rescale accumulator (rare: defer-max) ----
        if (!skip) {
#pragma unroll
            for (int r = 0; r < 16; r++) {
                int qrow = (r & 3) + 8 * (r >> 2) + 4 * hi;
                float cr = corrw[w][qrow];
                accO0[r] *= cr; accO1[r] *= cr;
            }
        }

        // ---- PV ----
        __builtin_amdgcn_s_setprio(1);
#pragma unroll
        for (int ks = 0; ks < 4; ks++) {
            int off = ks * 16 + dh;
            int ia = (l31 * 64 + off) ^ swk;
            int ib = ((l31 + 32) * 64 + off) ^ swk;
            bf16x8 vh0 = *(const bf16x8*)&U[8192 + ia];
            bf16x8 vh1 = *(const bf16x8*)&U[8192 + ib];
            bf16x8 vl0 = *(const bf16x8*)&U[12288 + ia];
            bf16x8 vl1 = *(const bf16x8*)&U[12288 + ib];
            accO0 = MF(pa[ks], vh0, accO0);
            accO1 = MF(pa[ks], vh1, accO1);
            accO0 = MF(pa[ks], vl0, accO0);
            accO1 = MF(pa[ks], vl1, accO1);
        }
        __builtin_amdgcn_s_setprio(0);

        asm volatile("" ::: "memory");
        __builtin_amdgcn_s_barrier();
    }

    // ---- epilogue: O/l -> split bf16 planes directly ----
    if (lane < 32) lw[w][l31] = l_run;
#pragma unroll
    for (int r = 0; r < 16; r++) {
        int qrow = (r & 3) + 8 * (r >> 2) + 4 * hi;
        float inv = 1.0f / lw[w][qrow];
        float v0 = accO0[r] * inv;
        float v1 = accO1[r] * inv;
        size_t base = (size_t)(q0 + w * 32 + qrow) * (NH * HD) + hd_ * 64 + l31;
        ushort hh, ll;
        bsplit(v0, hh, ll);
        oH[base] = hh; oL[base] = ll;
        bsplit(v1, hh, ll);
        oH[base + 32] = hh; oL[base + 32] = ll;
    }
}

// ---------------------------------------------------------------------------
extern "C" void kernel_launch(void* const* d_in, const int* in_sizes, int n_in,
                              void* d_out, int out_size, void* d_ws, size_t ws_size,
                              hipStream_t stream) {
    const float* hidden = (const float*)d_in[0];
    const float* cosT   = (const float*)d_in[1];
    const float* sinT   = (const float*)d_in[2];
    // d_in[3] = attention_mask: exactly causal -> analytic
    const float* wq = (const float*)d_in[4];
    const float* wk = (const float*)d_in[5];
    const float* wv = (const float*)d_in[6];
    const float* wo = (const float*)d_in[7];
    float* out = (float*)d_out;

    char* wsb = (char*)d_ws;
    auto alloc = [&](size_t bytes) { char* p = wsb; wsb += (bytes + 255) & ~255ULL; return p; };
    float* q = (float*)alloc((size_t)NH * S_LEN * HD * 4);
    float* k = (float*)alloc((size_t)NKV * S_LEN * HD * 4);
    float* v = (float*)alloc((size_t)NKV * S_LEN * HD * 4);
    ushort* hidH = (ushort*)alloc((size_t)S_LEN * HIDDEN * 2);
    ushort* hidL = (ushort*)alloc((size_t)S_LEN * HIDDEN * 2);
    ushort* WcH  = (ushort*)alloc((size_t)3072 * HIDDEN * 2);
    ushort* WcL  = (ushort*)alloc((size_t)3072 * HIDDEN * 2);
    ushort* woH  = (ushort*)alloc((size_t)HIDDEN * 2048 * 2);
    ushort* woL  = (ushort*)alloc((size_t)HIDDEN * 2048 * 2);
    ushort* oH   = (ushort*)alloc((size_t)S_LEN * 2048 * 2);
    ushort* oL   = (ushort*)alloc((size_t)S_LEN * 2048 * 2);
    // K/V planes alias hidH (dead after the QKV GEMM): 4 x 1,048,576 ushorts.
    ushort* khi  = hidH;
    ushort* klo  = hidH + 1048576;
    ushort* vthi = hidH + 2097152;
    ushort* vtlo = hidH + 3145728;

    dim3 blk(256);
    {
        int n4 = S_LEN * HIDDEN / 4;
        split_bf16<<<(n4 + 255) / 256, blk, 0, stream>>>(hidden, hidH, hidL, n4);
        int nq4 = NH * HD * HIDDEN / 4;
        split_bf16<<<(nq4 + 255) / 256, blk, 0, stream>>>(wq, WcH, WcL, nq4);
        int nk4 = NKV * HD * HIDDEN / 4;
        size_t off = (size_t)NH * HD * HIDDEN;
        split_bf16<<<(nk4 + 255) / 256, blk, 0, stream>>>(wk, WcH + off, WcL + off, nk4);
        size_t off2 = off + (size_t)NKV * HD * HIDDEN;
        split_bf16<<<(nk4 + 255) / 256, blk, 0, stream>>>(wv, WcH + off2, WcL + off2, nk4);
        int nw4 = HIDDEN * 2048 / 4;
        split_bf16<<<(nw4 + 255) / 256, blk, 0, stream>>>(wo, woH, woL, nw4);
    }
    // QKV projection: M=2048 (32 blocks), N=3072 (24 blocks) -> 768 (%8==0)
    mfma_gemm<0><<<dim3(32 * 24), blk, 0, stream>>>(
        hidH, hidL, WcH, WcL, q, k, v, 0, 32);
    // RoPE (q in place) + K split planes (overwrites hidH region — now dead)
    rope_split<<<(NH + NKV) * S_LEN * 32 / 256, blk, 0, stream>>>(
        q, k, cosT, sinT, khi, klo);
    // V^T split planes
    split_vt<<<NKV * (S_LEN / 64), blk, 0, stream>>>(v, vthi, vtlo);
    // flash attention -> split O planes (1-D grid, complement-paired)
    attn_mfma<<<dim3(512), blk, 0, stream>>>(
        q, khi, klo, vthi, vtlo, oH, oL);
    // out projection: M=2048 (32), N=2048 (16) -> 512 blocks (%8==0)
    mfma_gemm<1><<<dim3(32 * 16), blk, 0, stream>>>(
        oH, oL, woH, woL, out, nullptr, nullptr, 2048, 32);
}

// Round 11
// 381.468 us; speedup vs baseline: 3.5710x; 1.0117x over previous
//
#include <hip/hip_runtime.h>
#include <hip/hip_bf16.h>
#include <stdint.h>

// Fused GQA attention layer.
// Round 10b (resubmit; R10 bench failed at GPU acquisition): GEMM
// double-buffered staging with counted vmcnt(6) + raw barriers (same T3/T4
// recipe validated in attn_mfma in R9). Attention unchanged.
// Note: R4's LDS read-swizzle did NOT reduce SQ_LDS_BANK_CONFLICT (identical
// 9.4M pre/post) — conflicts are write-path/structural; kept anyway (free).

#define S_LEN 2048
#define HIDDEN 2048
#define NH 32
#define NKV 8
#define HD 64
// SCALE * log2(e): scores computed directly in exp2 domain
#define SCALE_L2E 0.18033688011112042f

typedef __bf16 bf16x8 __attribute__((ext_vector_type(8)));
typedef float f32x4 __attribute__((ext_vector_type(4)));
typedef float f32x16 __attribute__((ext_vector_type(16)));

__device__ inline void gload16(const void* g, void* l) {
    using GP = const __attribute__((address_space(1))) uint32_t*;
    using LP = __attribute__((address_space(3))) uint32_t*;
    __builtin_amdgcn_global_load_lds((GP)g, (LP)(uint32_t)(uintptr_t)l, 16, 0, 0);
}

__device__ inline ushort bf16r(float x) {
    uint32_t u = __float_as_uint(x);
    return (ushort)((u + 0x7FFFu + ((u >> 16) & 1u)) >> 16);
}
__device__ inline void bsplit(float x, ushort& h, ushort& l) {
    uint32_t u = __float_as_uint(x);
    uint32_t hr = (u + 0x7FFFu + ((u >> 16) & 1u)) >> 16;
    float r = x - __uint_as_float(hr << 16);
    uint32_t ul = __float_as_uint(r);
    l = (ushort)((ul + 0x7FFFu + ((ul >> 16) & 1u)) >> 16);
    h = (ushort)hr;
}
__device__ inline uint32_t pk2(float a, float b) {
    return (uint32_t)bf16r(a) | ((uint32_t)bf16r(b) << 16);
}

// ---------------------------------------------------------------------------
// fp32 -> (bf16 hi, bf16 lo) planes, vectorized x4.
// ---------------------------------------------------------------------------
__global__ __launch_bounds__(256) void split_bf16(
    const float* __restrict__ src, ushort* __restrict__ hi,
    ushort* __restrict__ lo, int n4)
{
    int i = blockIdx.x * 256 + threadIdx.x;
    if (i >= n4) return;
    float4 v = ((const float4*)src)[i];
    float x[4] = {v.x, v.y, v.z, v.w};
    ushort h[4], l[4];
#pragma unroll
    for (int j = 0; j < 4; j++) bsplit(x[j], h[j], l[j]);
    ushort4 ho = {h[0], h[1], h[2], h[3]};
    ushort4 lv = {l[0], l[1], l[2], l[3]};
    ((ushort4*)hi)[i] = ho;
    ((ushort4*)lo)[i] = lv;
}

// ---------------------------------------------------------------------------
// Split-bf16 MFMA GEMM, double-buffered staging (counted vmcnt, raw barriers).
// C[m][n] = sum_k A[m][k]*Bw[n][k], K=2048. Tile 64x128, BK=32, 4 waves.
// ---------------------------------------------------------------------------
__device__ inline int swz_idx(int row, int fk) {
    int line = row >> 1;
    int inner = (((fk << 1) | (row & 1)) ^ (line & 7));
    return line * 64 + inner * 8;
}

template <int MODE>
__global__ __launch_bounds__(256) void mfma_gemm(
    const ushort* __restrict__ Ah, const ushort* __restrict__ Al,
    const ushort* __restrict__ Bh, const ushort* __restrict__ Bl,
    float* __restrict__ C0, float* __restrict__ C1, float* __restrict__ C2,
    int ldc, int nbx)
{
    __shared__ ushort sAh[2][64 * 32], sAl[2][64 * 32];
    __shared__ ushort sBh[2][128 * 32], sBl[2][128 * 32];

    const int t = threadIdx.x;
    const int per = (int)gridDim.x >> 3;
    const int id = (blockIdx.x & 7) * per + (blockIdx.x >> 3);
    const int m0 = (id % nbx) * 64;
    const int n0 = (id / nbx) * 128;

    const int lineA = t >> 3;
    const int uA = (t & 7) ^ (lineA & 7);
    const int rowA = lineA * 2 + (uA & 1);
    const int kA = (uA >> 1) * 8;
    const ushort* aH = Ah + (size_t)(m0 + rowA) * HIDDEN + kA;
    const ushort* aL = Al + (size_t)(m0 + rowA) * HIDDEN + kA;
    const ushort* bH0 = Bh + (size_t)(n0 + rowA) * HIDDEN + kA;
    const ushort* bH1 = Bh + (size_t)(n0 + 64 + rowA) * HIDDEN + kA;
    const ushort* bL0 = Bl + (size_t)(n0 + rowA) * HIDDEN + kA;
    const ushort* bL1 = Bl + (size_t)(n0 + 64 + rowA) * HIDDEN + kA;

    const int lane = t & 63, w = t >> 6;
    const int fr = lane & 15;
    const int fk = lane >> 4;

    int idxA[4], idxB[2];
#pragma unroll
    for (int fi = 0; fi < 4; fi++) idxA[fi] = swz_idx(fi * 16 + fr, fk);
#pragma unroll
    for (int fj = 0; fj < 2; fj++) idxB[fj] = swz_idx(w * 32 + fj * 16 + fr, fk);

    f32x4 acc[4][2];
#pragma unroll
    for (int i = 0; i < 4; i++)
#pragma unroll
        for (int j = 0; j < 2; j++) acc[i][j] = {0.f, 0.f, 0.f, 0.f};

    auto STAGE = [&](int k0, int b) {
        gload16(aH + k0, sAh[b] + t * 8);
        gload16(aL + k0, sAl[b] + t * 8);
        gload16(bH0 + k0, sBh[b] + t * 8);
        gload16(bH1 + k0, sBh[b] + 2048 + t * 8);
        gload16(bL0 + k0, sBl[b] + t * 8);
        gload16(bL1 + k0, sBl[b] + 2048 + t * 8);
    };

    STAGE(0, 0);
    const int NSTEP = HIDDEN / 32;
    for (int i = 0; i < NSTEP; i++) {
        const int cur = i & 1;
        if (i + 1 < NSTEP) {
            STAGE((i + 1) * 32, cur ^ 1);
            asm volatile("s_waitcnt vmcnt(6)" ::: "memory");  // own 6 tile-i loads done
        } else {
            asm volatile("s_waitcnt vmcnt(0)" ::: "memory");
        }
        __builtin_amdgcn_s_barrier();  // all waves' tile-i loads done

        bf16x8 ah[4], al[4], bh[2], bl[2];
#pragma unroll
        for (int fi = 0; fi < 4; fi++) {
            ah[fi] = *(const bf16x8*)&sAh[cur][idxA[fi]];
            al[fi] = *(const bf16x8*)&sAl[cur][idxA[fi]];
        }
#pragma unroll
        for (int fj = 0; fj < 2; fj++) {
            bh[fj] = *(const bf16x8*)&sBh[cur][idxB[fj]];
            bl[fj] = *(const bf16x8*)&sBl[cur][idxB[fj]];
        }
#pragma unroll
        for (int fi = 0; fi < 4; fi++)
#pragma unroll
            for (int fj = 0; fj < 2; fj++) {
                acc[fi][fj] = __builtin_amdgcn_mfma_f32_16x16x32_bf16(
                    ah[fi], bh[fj], acc[fi][fj], 0, 0, 0);
                acc[fi][fj] = __builtin_amdgcn_mfma_f32_16x16x32_bf16(
                    ah[fi], bl[fj], acc[fi][fj], 0, 0, 0);
                acc[fi][fj] = __builtin_amdgcn_mfma_f32_16x16x32_bf16(
                    al[fi], bh[fj], acc[fi][fj], 0, 0, 0);
            }
        // MFMA consumed all ds_reads (lgkmcnt drained); barrier keeps next
        // iteration's STAGE (into buf cur) after everyone's reads of buf cur
        __builtin_amdgcn_s_barrier();
    }

#pragma unroll
    for (int fi = 0; fi < 4; fi++)
#pragma unroll
        for (int fj = 0; fj < 2; fj++) {
            int row0 = m0 + fi * 16 + fk * 4;
            int gcol = n0 + w * 32 + fj * 16 + fr;
            if (MODE == 0) {
                int slot = gcol >> 6, cin = gcol & 63;
                float* dst;
                if (slot < NH) dst = C0 + (size_t)slot * S_LEN * HD;
                else if (slot < NH + NKV) dst = C1 + (size_t)(slot - NH) * S_LEN * HD;
                else dst = C2 + (size_t)(slot - NH - NKV) * S_LEN * HD;
#pragma unroll
                for (int i = 0; i < 4; i++)
                    dst[(size_t)(row0 + i) * HD + cin] = acc[fi][fj][i];
            } else {
#pragma unroll
                for (int i = 0; i < 4; i++)
                    C0[(size_t)(row0 + i) * ldc + gcol] = acc[fi][fj][i];
            }
        }
}

// ---------------------------------------------------------------------------
// RoPE: q in-place fp32; k -> rope'd, split hi/lo, XOR-swizzled bf16 planes.
// ---------------------------------------------------------------------------
__global__ __launch_bounds__(256) void rope_split(
    float* __restrict__ qd, const float* __restrict__ kd,
    const float* __restrict__ cosT, const float* __restrict__ sinT,
    ushort* __restrict__ khi, ushort* __restrict__ klo)
{
    int idx = blockIdx.x * 256 + threadIdx.x;
    int d = idx & 31;
    int s = (idx >> 5) & (S_LEN - 1);
    int slot = idx >> 16;
    float c = cosT[s * HD + d];
    float sn = sinT[s * HD + d];
    if (slot < NH) {
        float* base = qd + ((size_t)slot * S_LEN + s) * HD;
        float x1 = base[d], x2 = base[d + 32];
        base[d] = x1 * c - x2 * sn;
        base[d + 32] = x2 * c + x1 * sn;
    } else {
        const float* base = kd + ((size_t)(slot - NH) * S_LEN + s) * HD;
        float x1 = base[d], x2 = base[d + 32];
        float y1 = x1 * c - x2 * sn;
        float y2 = x2 * c + x1 * sn;
        int sw = (s & 7) << 3;
        size_t rb = ((size_t)(slot - NH) * S_LEN + s) * 64;
        ushort h1, l1, h2, l2;
        bsplit(y1, h1, l1);
        bsplit(y2, h2, l2);
        khi[rb + (d ^ sw)] = h1;        klo[rb + (d ^ sw)] = l1;
        khi[rb + ((d + 32) ^ sw)] = h2; klo[rb + ((d + 32) ^ sw)] = l2;
    }
}

// ---------------------------------------------------------------------------
// V -> V^T split planes, swizzled (unchanged).
// ---------------------------------------------------------------------------
__global__ __launch_bounds__(256) void split_vt(
    const float* __restrict__ v, ushort* __restrict__ vthi,
    ushort* __restrict__ vtlo)
{
    __shared__ float tile[64][65];
    const int b = blockIdx.x;
    const int hk = b >> 5, kt = b & 31;
    const float* src = v + ((size_t)hk * S_LEN + kt * 64) * 64;
    const int t = threadIdx.x;
    {
        int row = t >> 2, dg = (t & 3) * 16;
#pragma unroll
        for (int i = 0; i < 4; i++) {
            float4 x = *(const float4*)(src + row * 64 + dg + i * 4);
            tile[row][dg + i * 4 + 0] = x.x;
            tile[row][dg + i * 4 + 1] = x.y;
            tile[row][dg + i * 4 + 2] = x.z;
            tile[row][dg + i * 4 + 3] = x.w;
        }
    }
    __syncthreads();
    const int d = t >> 2, kg = (t & 3) * 16;
    ushort hi16[16], lo16[16];
#pragma unroll
    for (int i = 0; i < 16; i++) bsplit(tile[kg + i][d], hi16[i], lo16[i]);
    const int sw = (d & 7) << 3;
    size_t rowb = ((size_t)hk * 64 + d) * S_LEN + kt * 64;
    int base = kg ^ (sw & 48);
    int o0 = base + (sw & 8);
    int o1 = base + (8 ^ (sw & 8));
    *(ushort4*)&vthi[rowb + o0]     = *(ushort4*)&hi16[0];
    *(ushort4*)&vthi[rowb + o0 + 4] = *(ushort4*)&hi16[4];
    *(ushort4*)&vthi[rowb + o1]     = *(ushort4*)&hi16[8];
    *(ushort4*)&vthi[rowb + o1 + 4] = *(ushort4*)&hi16[12];
    *(ushort4*)&vtlo[rowb + o0]     = *(ushort4*)&lo16[0];
    *(ushort4*)&vtlo[rowb + o0 + 4] = *(ushort4*)&lo16[4];
    *(ushort4*)&vtlo[rowb + o1]     = *(ushort4*)&lo16[8];
    *(ushort4*)&vtlo[rowb + o1 + 4] = *(ushort4*)&lo16[12];
}

// ---------------------------------------------------------------------------
// MFMA flash attention (unchanged from R9 — verified working).
// ---------------------------------------------------------------------------
__global__ __launch_bounds__(256, 2) void attn_mfma(
    const float* __restrict__ q,
    const ushort* __restrict__ khi, const ushort* __restrict__ klo,
    const ushort* __restrict__ vthi, const ushort* __restrict__ vtlo,
    ushort* __restrict__ oH, ushort* __restrict__ oL)
{
    __shared__ ushort uni[2][16384];
    __shared__ float corrw[4][32];
    __shared__ float lw[4][32];

    const int t = threadIdx.x;
    const int lane = t & 63, w = t >> 6;
    const int hi = lane >> 5;
    const int l31 = lane & 31;
    const int dh = hi * 8;

    const int id = blockIdx.x;
    const int hd_ = id & 31;
    const int g = id >> 5;
    const int qt = (g < 8) ? (15 - g) : (g - 8);
    const int q0 = qt * 128;
    const int hk = hd_ >> 2;

    const ushort* khi_t = khi + (size_t)hk * S_LEN * 64;
    const ushort* klo_t = klo + (size_t)hk * S_LEN * 64;
    const ushort* vth_t = vthi + (size_t)hk * 64 * S_LEN;
    const ushort* vtl_t = vtlo + (size_t)hk * 64 * S_LEN;
    const int d0s = t >> 3, kks = (t & 7) * 8;
    const int swk = (l31 & 7) << 3;
    const int qg = q0 + w * 32 + l31;
    const int ntiles = 2 * qt + 2;

    auto MF = [](bf16x8 a, bf16x8 b, f32x16 c) {
        return __builtin_amdgcn_mfma_f32_32x32x16_bf16(a, b, c, 0, 0, 0);
    };
    auto STAGE = [&](int k0, ushort* buf) {
        const ushort* a = khi_t + (size_t)k0 * 64;
        const ushort* b = klo_t + (size_t)k0 * 64;
        gload16(a + t * 8, buf + t * 8);
        gload16(a + 2048 + t * 8, buf + 2048 + t * 8);
        gload16(b + t * 8, buf + 4096 + t * 8);
        gload16(b + 2048 + t * 8, buf + 6144 + t * 8);
        gload16(vth_t + (size_t)d0s * S_LEN + k0 + kks, buf + 8192 + t * 8);
        gload16(vth_t + (size_t)(d0s + 32) * S_LEN + k0 + kks, buf + 10240 + t * 8);
        gload16(vtl_t + (size_t)d0s * S_LEN + k0 + kks, buf + 12288 + t * 8);
        gload16(vtl_t + (size_t)(d0s + 32) * S_LEN + k0 + kks, buf + 14336 + t * 8);
    };

    STAGE(0, uni[0]);
    {
        const int row = t >> 1, dg = (t & 1) * 32;
        const float* src = q + ((size_t)hd_ * S_LEN + q0 + row) * HD + dg;
        const int sw = (row & 7) << 3;
#pragma unroll
        for (int i = 0; i < 8; i++) {
            float4 v4 = *(const float4*)(src + i * 4);
            float xs[4] = {v4.x, v4.y, v4.z, v4.w};
            ushort h4[4], l4[4];
#pragma unroll
            for (int j = 0; j < 4; j++) bsplit(xs[j] * SCALE_L2E, h4[j], l4[j]);
            int idx = (row * 64 + dg + i * 4) ^ sw;
            *(ushort4*)&uni[1][idx] = *(ushort4*)&h4[0];
            *(ushort4*)&uni[1][8192 + idx] = *(ushort4*)&l4[0];
        }
    }
    __syncthreads();
    bf16x8 qh[4], ql[4];
    {
        const int qrow = w * 32 + l31;
        const int sw = (qrow & 7) << 3;
#pragma unroll
        for (int ks = 0; ks < 4; ks++) {
            int idx = (qrow * 64 + ks * 16 + dh) ^ sw;
            qh[ks] = *(const bf16x8*)&uni[1][idx];
            ql[ks] = *(const bf16x8*)&uni[1][8192 + idx];
        }
    }
    __syncthreads();

    f32x16 accO0, accO1;
#pragma unroll
    for (int r = 0; r < 16; r++) { accO0[r] = 0.f; accO1[r] = 0.f; }
    float m_run = -1e30f, l_run = 0.f;

    for (int tile = 0; tile < ntiles; tile++) {
        const int k0 = tile * 64;
        const ushort* U = uni[tile & 1];
        if (tile + 1 < ntiles) {
            STAGE(k0 + 64, uni[(tile + 1) & 1]);
            asm volatile("s_waitcnt vmcnt(8)" ::: "memory");
        } else {
            asm volatile("s_waitcnt vmcnt(0)" ::: "memory");
        }
        __builtin_amdgcn_s_barrier();

        f32x16 sa0, sa1, sb0, sb1;
#pragma unroll
        for (int r = 0; r < 16; r++) { sa0[r] = 0.f; sa1[r] = 0.f; sb0[r] = 0.f; sb1[r] = 0.f; }
        __builtin_amdgcn_s_setprio(1);
#pragma unroll
        for (int ks = 0; ks < 2; ks++) {
            int off = ks * 16 + dh;
            int i0 = (l31 * 64 + off) ^ swk;
            int i1 = ((l31 + 32) * 64 + off) ^ swk;
            bf16x8 kh0 = *(const bf16x8*)&U[i0];
            bf16x8 kl0 = *(const bf16x8*)&U[4096 + i0];
            bf16x8 kh1 = *(const bf16x8*)&U[i1];
            bf16x8 kl1 = *(const bf16x8*)&U[4096 + i1];
            sa0 = MF(kh0, qh[ks], sa0); sa1 = MF(kh1, qh[ks], sa1);
            sa0 = MF(kh0, ql[ks], sa0); sa1 = MF(kh1, ql[ks], sa1);
            sa0 = MF(kl0, qh[ks], sa0); sa1 = MF(kl1, qh[ks], sa1);
        }
#pragma unroll
        for (int ks = 2; ks < 4; ks++) {
            int off = ks * 16 + dh;
            int i0 = (l31 * 64 + off) ^ swk;
            int i1 = ((l31 + 32) * 64 + off) ^ swk;
            bf16x8 kh0 = *(const bf16x8*)&U[i0];
            bf16x8 kl0 = *(const bf16x8*)&U[4096 + i0];
            bf16x8 kh1 = *(const bf16x8*)&U[i1];
            bf16x8 kl1 = *(const bf16x8*)&U[4096 + i1];
            sb0 = MF(kh0, qh[ks], sb0); sb1 = MF(kh1, qh[ks], sb1);
            sb0 = MF(kh0, ql[ks], sb0); sb1 = MF(kh1, ql[ks], sb1);
            sb0 = MF(kl0, qh[ks], sb0); sb1 = MF(kl1, qh[ks], sb1);
        }
        __builtin_amdgcn_s_setprio(0);
        f32x16 sc0 = sa0 + sb0;
        f32x16 sc1 = sa1 + sb1;

        if (tile >= 2 * qt) {
#pragma unroll
            for (int r = 0; r < 16; r++) {
                int krow = (r & 3) + 8 * (r >> 2) + 4 * hi;
                if (k0 + krow > qg) sc0[r] = -1e30f;
                if (k0 + 32 + krow > qg) sc1[r] = -1e30f;
            }
        }
        float mx = -1e30f;
#pragma unroll
        for (int r = 0; r < 16; r++) mx = fmaxf(mx, fmaxf(sc0[r], sc1[r]));
        mx = fmaxf(mx, __shfl_xor(mx, 32));

        const bool skip = __all(mx - m_run <= 8.0f);
        float corr = 1.f;
        if (!skip) {
            float m_new = fmaxf(m_run, mx);
            corr = exp2f(m_run - m_new);
            m_run = m_new;
            if (lane < 32) corrw[w][l31] = corr;
        }
        float sum = 0.f;
#pragma unroll
        for (int r = 0; r < 16; r++) {
            float p0 = exp2f(sc0[r] - m_run);
            float p1 = exp2f(sc1[r] - m_run);
            sc0[r] = p0; sc1[r] = p1;
            sum += p0 + p1;
        }
        sum += __shfl_xor(sum, 32);
        l_run = l_run * corr + sum;

        bf16x8 pa[4];
        {
            uint32_t c0, c1, c2, c3;
            union { uint32_t u[4]; bf16x8 v; } uu;
#define BUILD_PA(SC, RB, DST)                                              \
            c0 = pk2((SC)[RB + 0], (SC)[RB + 1]);                          \
            c1 = pk2((SC)[RB + 2], (SC)[RB + 3]);                          \
            c2 = pk2((SC)[RB + 4], (SC)[RB + 5]);                          \
            c3 = pk2((SC)[RB + 6], (SC)[RB + 7]);                          \
            asm volatile("v_permlane32_swap_b32 %0, %1"                    \
                         : "+v"(c0), "+v"(c2));                            \
            asm volatile("v_permlane32_swap_b32 %0, %1"                    \
                         : "+v"(c1), "+v"(c3));                            \
            uu.u[0] = c0; uu.u[1] = c1; uu.u[2] = c2; uu.u[3] = c3;        \
            DST = uu.v;
            BUILD_PA(sc0, 0, pa[0]);
            BUILD_PA(sc0, 8, pa[1]);
            BUILD_PA(sc1, 0, pa[2]);
            BUILD_PA(sc1, 8, pa[3]);
#undef BUILD_PA
        }

        if (!skip) {
#pragma unroll
            for (int r = 0; r < 16; r++) {
                int qrow = (r & 3) + 8 * (r >> 2) + 4 * hi;
                float cr = corrw[w][qrow];
                accO0[r] *= cr; accO1[r] *= cr;
            }
        }

        __builtin_amdgcn_s_setprio(1);
#pragma unroll
        for (int ks = 0; ks < 4; ks++) {
            int off = ks * 16 + dh;
            int ia = (l31 * 64 + off) ^ swk;
            int ib = ((l31 + 32) * 64 + off) ^ swk;
            bf16x8 vh0 = *(const bf16x8*)&U[8192 + ia];
            bf16x8 vh1 = *(const bf16x8*)&U[8192 + ib];
            bf16x8 vl0 = *(const bf16x8*)&U[12288 + ia];
            bf16x8 vl1 = *(const bf16x8*)&U[12288 + ib];
            accO0 = MF(pa[ks], vh0, accO0);
            accO1 = MF(pa[ks], vh1, accO1);
            accO0 = MF(pa[ks], vl0, accO0);
            accO1 = MF(pa[ks], vl1, accO1);
        }
        __builtin_amdgcn_s_setprio(0);

        asm volatile("" ::: "memory");
        __builtin_amdgcn_s_barrier();
    }

    if (lane < 32) lw[w][l31] = l_run;
#pragma unroll
    for (int r = 0; r < 16; r++) {
        int qrow = (r & 3) + 8 * (r >> 2) + 4 * hi;
        float inv = 1.0f / lw[w][qrow];
        float v0 = accO0[r] * inv;
        float v1 = accO1[r] * inv;
        size_t base = (size_t)(q0 + w * 32 + qrow) * (NH * HD) + hd_ * 64 + l31;
        ushort hh, ll;
        bsplit(v0, hh, ll);
        oH[base] = hh; oL[base] = ll;
        bsplit(v1, hh, ll);
        oH[base + 32] = hh; oL[base + 32] = ll;
    }
}

// ---------------------------------------------------------------------------
extern "C" void kernel_launch(void* const* d_in, const int* in_sizes, int n_in,
                              void* d_out, int out_size, void* d_ws, size_t ws_size,
                              hipStream_t stream) {
    const float* hidden = (const float*)d_in[0];
    const float* cosT   = (const float*)d_in[1];
    const float* sinT   = (const float*)d_in[2];
    // d_in[3] = attention_mask: exactly causal -> analytic
    const float* wq = (const float*)d_in[4];
    const float* wk = (const float*)d_in[5];
    const float* wv = (const float*)d_in[6];
    const float* wo = (const float*)d_in[7];
    float* out = (float*)d_out;

    char* wsb = (char*)d_ws;
    auto alloc = [&](size_t bytes) { char* p = wsb; wsb += (bytes + 255) & ~255ULL; return p; };
    float* q = (float*)alloc((size_t)NH * S_LEN * HD * 4);
    float* k = (float*)alloc((size_t)NKV * S_LEN * HD * 4);
    float* v = (float*)alloc((size_t)NKV * S_LEN * HD * 4);
    ushort* hidH = (ushort*)alloc((size_t)S_LEN * HIDDEN * 2);
    ushort* hidL = (ushort*)alloc((size_t)S_LEN * HIDDEN * 2);
    ushort* WcH  = (ushort*)alloc((size_t)3072 * HIDDEN * 2);
    ushort* WcL  = (ushort*)alloc((size_t)3072 * HIDDEN * 2);
    ushort* woH  = (ushort*)alloc((size_t)HIDDEN * 2048 * 2);
    ushort* woL  = (ushort*)alloc((size_t)HIDDEN * 2048 * 2);
    ushort* oH   = (ushort*)alloc((size_t)S_LEN * 2048 * 2);
    ushort* oL   = (ushort*)alloc((size_t)S_LEN * 2048 * 2);
    // K/V planes alias hidH (dead after the QKV GEMM): 4 x 1,048,576 ushorts.
    ushort* khi  = hidH;
    ushort* klo  = hidH + 1048576;
    ushort* vthi = hidH + 2097152;
    ushort* vtlo = hidH + 3145728;

    dim3 blk(256);
    {
        int n4 = S_LEN * HIDDEN / 4;
        split_bf16<<<(n4 + 255) / 256, blk, 0, stream>>>(hidden, hidH, hidL, n4);
        int nq4 = NH * HD * HIDDEN / 4;
        split_bf16<<<(nq4 + 255) / 256, blk, 0, stream>>>(wq, WcH, WcL, nq4);
        int nk4 = NKV * HD * HIDDEN / 4;
        size_t off = (size_t)NH * HD * HIDDEN;
        split_bf16<<<(nk4 + 255) / 256, blk, 0, stream>>>(wk, WcH + off, WcL + off, nk4);
        size_t off2 = off + (size_t)NKV * HD * HIDDEN;
        split_bf16<<<(nk4 + 255) / 256, blk, 0, stream>>>(wv, WcH + off2, WcL + off2, nk4);
        int nw4 = HIDDEN * 2048 / 4;
        split_bf16<<<(nw4 + 255) / 256, blk, 0, stream>>>(wo, woH, woL, nw4);
    }
    // QKV projection: M=2048 (32 blocks), N=3072 (24 blocks) -> 768 (%8==0)
    mfma_gemm<0><<<dim3(32 * 24), blk, 0, stream>>>(
        hidH, hidL, WcH, WcL, q, k, v, 0, 32);
    // RoPE (q in place) + K split planes (overwrites hidH region — now dead)
    rope_split<<<(NH + NKV) * S_LEN * 32 / 256, blk, 0, stream>>>(
        q, k, cosT, sinT, khi, klo);
    // V^T split planes
    split_vt<<<NKV * (S_LEN / 64), blk, 0, stream>>>(v, vthi, vtlo);
    // flash attention -> split O planes (1-D grid, complement-paired)
    attn_mfma<<<dim3(512), blk, 0, stream>>>(
        q, khi, klo, vthi, vtlo, oH, oL);
    // out projection: M=2048 (32), N=2048 (16) -> 512 blocks (%8==0)
    mfma_gemm<1><<<dim3(32 * 16), blk, 0, stream>>>(
        oH, oL, woH, woL, out, nullptr, nullptr, 2048, 32);
}